// Round 2
// baseline (2222.878 us; speedup 1.0000x reference)
//
#include <hip/hip_runtime.h>
#include <math.h>

typedef unsigned short u16;
typedef u16 u16x8 __attribute__((ext_vector_type(8)));
typedef u16 u16x4 __attribute__((ext_vector_type(4)));
typedef float f32x4 __attribute__((ext_vector_type(4)));

__device__ __forceinline__ float b2f(u16 u) {
  return __uint_as_float(((unsigned)u) << 16);
}
__device__ __forceinline__ u16 f2b(float f) {
  unsigned x = __float_as_uint(f);
  unsigned r = x + 0x7fffu + ((x >> 16) & 1u);
  return (u16)(r >> 16);
}

// generic scalar load / store (fp32 or bf16-as-u16)
__device__ __forceinline__ float ld1(const float* p) { return *p; }
__device__ __forceinline__ float ld1(const u16* p)   { return b2f(*p); }
__device__ __forceinline__ void st1(float* p, float v) { *p = v; }
__device__ __forceinline__ void st1(u16* p, float v)   { *p = f2b(v); }

// load 8 consecutive elements into fp32
__device__ __forceinline__ void load8(const float* p, float* d) {
  f32x4 a = *(const f32x4*)p;
  f32x4 b = *(const f32x4*)(p + 4);
  d[0]=a[0]; d[1]=a[1]; d[2]=a[2]; d[3]=a[3];
  d[4]=b[0]; d[5]=b[1]; d[6]=b[2]; d[7]=b[3];
}
__device__ __forceinline__ void load8(const u16* p, float* d) {
  u16x8 v = *(const u16x8*)p;
#pragma unroll
  for (int j = 0; j < 8; ++j) d[j] = b2f(v[j]);
}

#define SCALE 0.125f

// ---------------------------------------------------------------------------
// Big GEMM: C[M x 512] = A[M x 512] @ W[512 x 512] (+epilogue)
// GATE==0: C = acc + bias[col]
// GATE==1: z = acc + gateblk[brow][col]; g = sigmoid(z);
//          C = g * A[row][col] + (1-g) * gout[brow][col]   (A = local_out)
// Tile: BM=BN=64, BK=32; 256 threads; each thread computes 4x4.
// ---------------------------------------------------------------------------
template<int GATE, typename TA, typename TC>
__global__ __launch_bounds__(256)
void gemm512(const TA* __restrict__ A, const float* __restrict__ W,
             const float* __restrict__ bias, TC* __restrict__ C,
             const float* __restrict__ gateblk, const float* __restrict__ gout)
{
  __shared__ float As[32][68];   // [k][m]
  __shared__ float Ws[32][68];   // [k][n]
  const int tid = threadIdx.x;
  const int tx = tid & 15, ty = tid >> 4;
  const int m0 = blockIdx.y * 64;
  const int n0 = blockIdx.x * 64;
  const int arow  = tid >> 2;        // 0..63
  const int akoff = (tid & 3) * 8;   // 0,8,16,24
  const int wrow  = tid >> 3;        // 0..31
  const int wnoff = (tid & 7) * 8;   // 0..56
  float acc[4][4] = {};
  for (int k0 = 0; k0 < 512; k0 += 32) {
    float av[8], wv[8];
    load8(A + (size_t)(m0 + arow) * 512 + k0 + akoff, av);
    load8(W + (size_t)(k0 + wrow) * 512 + n0 + wnoff, wv);
    __syncthreads();
#pragma unroll
    for (int j = 0; j < 8; ++j) As[akoff + j][arow] = av[j];
#pragma unroll
    for (int j = 0; j < 8; ++j) Ws[wrow][wnoff + j] = wv[j];
    __syncthreads();
#pragma unroll
    for (int kk = 0; kk < 32; ++kk) {
      f32x4 a = *(const f32x4*)&As[kk][ty * 4];
      f32x4 b = *(const f32x4*)&Ws[kk][tx * 4];
#pragma unroll
      for (int r = 0; r < 4; ++r)
#pragma unroll
        for (int c = 0; c < 4; ++c)
          acc[r][c] = fmaf(a[r], b[c], acc[r][c]);
    }
  }
#pragma unroll
  for (int r = 0; r < 4; ++r) {
    const int row = m0 + ty * 4 + r;
    const int col = n0 + tx * 4;
    if (GATE == 0) {
#pragma unroll
      for (int c = 0; c < 4; ++c)
        st1(C + (size_t)row * 512 + col + c, acc[r][c] + bias[col + c]);
    } else {
      const int brow = row >> 9;     // token block (b*16 + sblk)
#pragma unroll
      for (int c = 0; c < 4; ++c) {
        float z = acc[r][c] + gateblk[brow * 512 + col + c];
        float g = 1.f / (1.f + __expf(-z));
        float lo = ld1(A + (size_t)row * 512 + col + c);
        float go = gout[brow * 512 + col + c];
        st1(C + (size_t)row * 512 + col + c, g * lo + (1.f - g) * go);
      }
    }
  }
}

// ---------------------------------------------------------------------------
// Block-local attention. grid = (2, 64, 8): 256 queries per (y-block), one
// (token-block g, head h) per (y,z). One query per thread, online softmax,
// K/V staged 64 keys at a time in LDS as fp32. Q/K/V/CTX are bf16.
// ---------------------------------------------------------------------------
__global__ __launch_bounds__(256)
void attn_local(const u16* __restrict__ Q, const u16* __restrict__ K,
                const u16* __restrict__ V, u16* __restrict__ CTX)
{
  __shared__ float Ks[64][68];
  __shared__ float Vs[64][68];
  const int tid = threadIdx.x;
  const int g = blockIdx.y;
  const int h = blockIdx.z;
  const int t0 = g * 512;
  const int tq = t0 + blockIdx.x * 256 + tid;
  const int fb = h * 64;

  float q[64];
  load8(Q + (size_t)tq * 512 + fb,      q);
  load8(Q + (size_t)tq * 512 + fb + 8,  q + 8);
  load8(Q + (size_t)tq * 512 + fb + 16, q + 16);
  load8(Q + (size_t)tq * 512 + fb + 24, q + 24);
  load8(Q + (size_t)tq * 512 + fb + 32, q + 32);
  load8(Q + (size_t)tq * 512 + fb + 40, q + 40);
  load8(Q + (size_t)tq * 512 + fb + 48, q + 48);
  load8(Q + (size_t)tq * 512 + fb + 56, q + 56);

  float ctx[64];
#pragma unroll
  for (int d = 0; d < 64; ++d) ctx[d] = 0.f;
  float m = -INFINITY, l = 0.f;

  const int skey = tid >> 2;        // 0..63
  const int sd   = (tid & 3) * 16;  // 0,16,32,48

  for (int kc = 0; kc < 8; ++kc) {
    __syncthreads();
    {
      const u16* kp = K + (size_t)(t0 + kc * 64 + skey) * 512 + fb + sd;
      const u16* vp = V + (size_t)(t0 + kc * 64 + skey) * 512 + fb + sd;
      float a[8], b[8], c[8], d8[8];
      load8(kp, a); load8(kp + 8, b); load8(vp, c); load8(vp + 8, d8);
#pragma unroll
      for (int j = 0; j < 8; ++j) {
        Ks[skey][sd + j]     = a[j];
        Ks[skey][sd + 8 + j] = b[j];
        Vs[skey][sd + j]     = c[j];
        Vs[skey][sd + 8 + j] = d8[j];
      }
    }
    __syncthreads();
    for (int key = 0; key < 64; ++key) {
      float s = 0.f;
#pragma unroll
      for (int j = 0; j < 16; ++j) {
        f32x4 kv = *(const f32x4*)&Ks[key][j * 4];
        s += q[j*4+0]*kv[0] + q[j*4+1]*kv[1] + q[j*4+2]*kv[2] + q[j*4+3]*kv[3];
      }
      s *= SCALE;
      if (s <= m) {
        float p = __expf(s - m);
        l += p;
#pragma unroll
        for (int j = 0; j < 16; ++j) {
          f32x4 vv = *(const f32x4*)&Vs[key][j * 4];
          ctx[j*4+0] = fmaf(p, vv[0], ctx[j*4+0]);
          ctx[j*4+1] = fmaf(p, vv[1], ctx[j*4+1]);
          ctx[j*4+2] = fmaf(p, vv[2], ctx[j*4+2]);
          ctx[j*4+3] = fmaf(p, vv[3], ctx[j*4+3]);
        }
      } else {
        float r = __expf(m - s);
        m = s;
        l = l * r + 1.f;
#pragma unroll
        for (int j = 0; j < 16; ++j) {
          f32x4 vv = *(const f32x4*)&Vs[key][j * 4];
          ctx[j*4+0] = fmaf(ctx[j*4+0], r, vv[0]);
          ctx[j*4+1] = fmaf(ctx[j*4+1], r, vv[1]);
          ctx[j*4+2] = fmaf(ctx[j*4+2], r, vv[2]);
          ctx[j*4+3] = fmaf(ctx[j*4+3], r, vv[3]);
        }
      }
    }
  }
  const float inv = 1.f / l;
  u16* cp = CTX + (size_t)tq * 512 + fb;
#pragma unroll
  for (int j = 0; j < 16; ++j) {
    u16x4 p;
#pragma unroll
    for (int c = 0; c < 4; ++c) p[c] = f2b(ctx[j * 4 + c] * inv);
    *(u16x4*)(cp + j * 4) = p;
  }
}

// ---------------------------------------------------------------------------
// Pooled block means: P[64][512] = mean over 512 tokens of x (fp32)
// ---------------------------------------------------------------------------
__global__ __launch_bounds__(256)
void pool_mean(const float* __restrict__ X, float* __restrict__ P)
{
  const int g = blockIdx.x;
  const int tid = threadIdx.x;
  const float* xp = X + (size_t)g * 512 * 512;
  float a0 = 0.f, a1 = 0.f;
  for (int t = 0; t < 512; ++t) {
    a0 += xp[t * 512 + tid];
    a1 += xp[t * 512 + tid + 256];
  }
  P[g * 512 + tid]       = a0 * (1.f / 512.f);
  P[g * 512 + tid + 256] = a1 * (1.f / 512.f);
}

// ---------------------------------------------------------------------------
// Small GEMM: Out[64 x 512] (f32) = A[64 x 512] (f32) @ W[512 x 512] (f32)
//             + bias (f32). One block per row.
// ---------------------------------------------------------------------------
__global__ __launch_bounds__(256)
void small_gemm(const float* __restrict__ A, const float* __restrict__ W,
                const float* __restrict__ bias, float* __restrict__ Out)
{
  __shared__ float a[512];
  const int r = blockIdx.x;
  const int tid = threadIdx.x;
  a[tid]       = A[(size_t)r * 512 + tid];
  a[tid + 256] = A[(size_t)r * 512 + tid + 256];
  __syncthreads();
  float acc0 = 0.f, acc1 = 0.f;
  for (int k = 0; k < 512; ++k) {
    const float av = a[k];
    acc0 = fmaf(av, W[(size_t)k * 512 + tid],       acc0);
    acc1 = fmaf(av, W[(size_t)k * 512 + tid + 256], acc1);
  }
  Out[(size_t)r * 512 + tid]       = acc0 + bias[tid];
  Out[(size_t)r * 512 + tid + 256] = acc1 + bias[tid + 256];
}

// ---------------------------------------------------------------------------
// Global attention over the 16 pooled block summaries of each batch.
// grid = 32 blocks: (b, h). All fp32.
// ---------------------------------------------------------------------------
__global__ __launch_bounds__(256)
void gattn(const float* __restrict__ Qg, const float* __restrict__ Kg,
           const float* __restrict__ Vg, float* __restrict__ Gl)
{
  __shared__ float q[16][64], k[16][64], v[16][64];
  __shared__ float sc[16][16];
  const int bh = blockIdx.x;
  const int b = bh >> 3, h = bh & 7;
  const int tid = threadIdx.x;
  for (int idx = tid; idx < 1024; idx += 256) {
    const int n = idx >> 6, d = idx & 63;
    const size_t off = (size_t)(b * 16 + n) * 512 + h * 64 + d;
    q[n][d] = Qg[off]; k[n][d] = Kg[off]; v[n][d] = Vg[off];
  }
  __syncthreads();
  {
    const int qq = tid >> 4, kk = tid & 15;
    float s = 0.f;
#pragma unroll
    for (int d = 0; d < 64; ++d) s = fmaf(q[qq][d], k[kk][d], s);
    sc[qq][kk] = s * SCALE;
  }
  __syncthreads();
  if (tid < 16) {
    float mx = -INFINITY;
#pragma unroll
    for (int j = 0; j < 16; ++j) mx = fmaxf(mx, sc[tid][j]);
    float e[16]; float sum = 0.f;
#pragma unroll
    for (int j = 0; j < 16; ++j) { e[j] = __expf(sc[tid][j] - mx); sum += e[j]; }
    const float inv = 1.f / sum;
#pragma unroll
    for (int j = 0; j < 16; ++j) sc[tid][j] = e[j] * inv;
  }
  __syncthreads();
  for (int idx = tid; idx < 1024; idx += 256) {
    const int qq = idx >> 6, d = idx & 63;
    float o = 0.f;
#pragma unroll
    for (int j = 0; j < 16; ++j) o = fmaf(sc[qq][j], v[j][d], o);
    Gl[(size_t)(b * 16 + qq) * 512 + h * 64 + d] = o;
  }
}

// ---------------------------------------------------------------------------
extern "C" void kernel_launch(void* const* d_in, const int* in_sizes, int n_in,
                              void* d_out, int out_size, void* d_ws, size_t ws_size,
                              hipStream_t stream)
{
  const float* x      = (const float*)d_in[0];
  const float* lq_w   = (const float*)d_in[1];
  const float* lq_b   = (const float*)d_in[2];
  const float* lk_w   = (const float*)d_in[3];
  const float* lk_b   = (const float*)d_in[4];
  const float* lv_w   = (const float*)d_in[5];
  const float* lv_b   = (const float*)d_in[6];
  const float* lo_w   = (const float*)d_in[7];
  const float* lo_b   = (const float*)d_in[8];
  const float* gq_w   = (const float*)d_in[9];
  const float* gq_b   = (const float*)d_in[10];
  const float* gk_w   = (const float*)d_in[11];
  const float* gk_b   = (const float*)d_in[12];
  const float* gv_w   = (const float*)d_in[13];
  const float* gv_b   = (const float*)d_in[14];
  const float* go_w   = (const float*)d_in[15];
  const float* go_b   = (const float*)d_in[16];
  const float* gate_w = (const float*)d_in[17];
  const float* gate_b = (const float*)d_in[18];
  float* out = (float*)d_out;

  const size_t NE = (size_t)32768 * 512;
  char* ws = (char*)d_ws;
  u16* Qb    = (u16*)ws;          // 32 MiB each
  u16* Kb    = Qb + NE;
  u16* Vb    = Kb + NE;
  u16* CTXb  = Vb + NE;
  u16* LOCAL = Qb;                // Q dead after attention; reuse
  // small fp32 scratch overlaid on Kb (dead after attn_local; global path
  // runs strictly after attention in stream order)
  float* fbase   = (float*)Kb;
  float* pooled  = fbase;            // 64*512
  float* Qg      = pooled + 32768;
  float* Kg      = Qg + 32768;
  float* Vg      = Kg + 32768;
  float* Gl      = Vg + 32768;
  float* GOUT    = Gl + 32768;
  float* GATEBLK = GOUT + 32768;

  const dim3 gg(8, 512), bb(256);
  gemm512<0, float, u16><<<gg, bb, 0, stream>>>(x, lq_w, lq_b, Qb, nullptr, nullptr);
  gemm512<0, float, u16><<<gg, bb, 0, stream>>>(x, lk_w, lk_b, Kb, nullptr, nullptr);
  gemm512<0, float, u16><<<gg, bb, 0, stream>>>(x, lv_w, lv_b, Vb, nullptr, nullptr);
  attn_local<<<dim3(2, 64, 8), 256, 0, stream>>>(Qb, Kb, Vb, CTXb);
  gemm512<0, u16, u16><<<gg, bb, 0, stream>>>(CTXb, lo_w, lo_b, LOCAL, nullptr, nullptr);

  pool_mean<<<64, 256, 0, stream>>>(x, pooled);
  small_gemm<<<64, 256, 0, stream>>>(pooled, gq_w, gq_b, Qg);
  small_gemm<<<64, 256, 0, stream>>>(pooled, gk_w, gk_b, Kg);
  small_gemm<<<64, 256, 0, stream>>>(pooled, gv_w, gv_b, Vg);
  gattn<<<32, 256, 0, stream>>>(Qg, Kg, Vg, Gl);
  small_gemm<<<64, 256, 0, stream>>>(Gl, go_w, go_b, GOUT);
  small_gemm<<<64, 256, 0, stream>>>(GOUT, gate_w + (size_t)512 * 512, gate_b, GATEBLK);

  gemm512<1, u16, float><<<gg, bb, 0, stream>>>(LOCAL, gate_w, nullptr, out, GATEBLK, GOUT);
}

// Round 3
// 422.390 us; speedup vs baseline: 5.2626x; 5.2626x over previous
//
#include <hip/hip_runtime.h>
#include <math.h>

typedef unsigned short u16;
typedef short s16;
typedef u16 u16x8 __attribute__((ext_vector_type(8)));
typedef s16 s16x8 __attribute__((ext_vector_type(8)));
typedef float f32x4 __attribute__((ext_vector_type(4)));

__device__ __forceinline__ float b2f(u16 u) {
  return __uint_as_float(((unsigned)u) << 16);
}
__device__ __forceinline__ u16 f2b(float f) {
  unsigned x = __float_as_uint(f);
  unsigned r = x + 0x7fffu + ((x >> 16) & 1u);
  return (u16)(r >> 16);
}

#define SCALE 0.125f
#define NTOK 32768           // 4 * 8192
#define DM   512

// ---------------------------------------------------------------------------
// convert x (fp32) -> bf16, 8 elems/thread
// ---------------------------------------------------------------------------
__global__ __launch_bounds__(256)
void conv_x(const float* __restrict__ X, u16* __restrict__ Xb)
{
  const size_t i = ((size_t)blockIdx.x * 256 + threadIdx.x) * 8;
  f32x4 a = *(const f32x4*)(X + i);
  f32x4 b = *(const f32x4*)(X + i + 4);
  u16x8 o;
  o[0]=f2b(a[0]); o[1]=f2b(a[1]); o[2]=f2b(a[2]); o[3]=f2b(a[3]);
  o[4]=f2b(b[0]); o[5]=f2b(b[1]); o[6]=f2b(b[2]); o[7]=f2b(b[3]);
  *(u16x8*)(Xb + i) = o;
}

// ---------------------------------------------------------------------------
// transpose-convert 5 weight matrices [512k][512n] fp32 -> Wt [512n][512k] bf16
// grid (16,16,5), block 256 (32x8)
// ---------------------------------------------------------------------------
__global__ __launch_bounds__(256)
void trans_w(const float* w0, const float* w1, const float* w2,
             const float* w3, const float* w4, u16* __restrict__ WT)
{
  __shared__ float t[32][33];
  const int z = blockIdx.z;
  const float* W = (z == 0) ? w0 : (z == 1) ? w1 : (z == 2) ? w2 : (z == 3) ? w3 : w4;
  u16* D = WT + (size_t)z * DM * DM;
  const int tx = threadIdx.x & 31, ty = threadIdx.x >> 5;
  const int n0 = blockIdx.x * 32, k0 = blockIdx.y * 32;
#pragma unroll
  for (int j = 0; j < 4; ++j)
    t[ty + j * 8][tx] = W[(size_t)(k0 + ty + j * 8) * DM + n0 + tx];
  __syncthreads();
#pragma unroll
  for (int j = 0; j < 4; ++j)
    D[(size_t)(n0 + ty + j * 8) * DM + k0 + tx] = f2b(t[tx][ty + j * 8]);
}

// ---------------------------------------------------------------------------
// MFMA GEMM: C[M x 512] = A[M x 512](bf16) @ Wt^T (Wt is [n][k] bf16)
// 128x128 tile, BK=64, 256 threads = 4 waves (2x2), 64x64 per wave.
// EPI 0: Cb = bf16((acc + bias[n]) * outscale)
// EPI 1: z = acc + GB[brow][n]; g = sigmoid(z);
//        Cf = g * bf16(A[m][n]) + (1-g) * GO[brow][n]     (A = LOCAL)
// ---------------------------------------------------------------------------
template<int EPI>
__global__ __launch_bounds__(256)
void gemm_mfma(const u16* __restrict__ A, const u16* __restrict__ Wt,
               const float* __restrict__ bias, u16* Cb, float* Cf,
               float outscale, const float* __restrict__ GB,
               const float* __restrict__ GO)
{
  __shared__ u16 As[128][72];
  __shared__ u16 Bs[128][72];
  const int tid = threadIdx.x;
  const int w = tid >> 6, l = tid & 63;
  const int l15 = l & 15, gl = l >> 4;
  const int wm = w >> 1, wn = w & 1;           // wave tile (wm*64, wn*64)
  const int m0 = blockIdx.y * 128;
  const int n0 = blockIdx.x * 128;

  f32x4 acc[4][4];
#pragma unroll
  for (int i = 0; i < 4; ++i)
#pragma unroll
    for (int j = 0; j < 4; ++j) acc[i][j] = {0.f, 0.f, 0.f, 0.f};

  for (int k0 = 0; k0 < DM; k0 += 64) {
    __syncthreads();
#pragma unroll
    for (int it = 0; it < 4; ++it) {
      const int chunk = it * 256 + tid;        // 0..1023
      const int row = chunk >> 3, c8 = (chunk & 7) * 8;
      *(s16x8*)&As[row][c8] = *(const s16x8*)(A  + (size_t)(m0 + row) * DM + k0 + c8);
      *(s16x8*)&Bs[row][c8] = *(const s16x8*)(Wt + (size_t)(n0 + row) * DM + k0 + c8);
    }
    __syncthreads();
#pragma unroll
    for (int kd = 0; kd < 2; ++kd) {
      s16x8 af[4], bf[4];
#pragma unroll
      for (int f = 0; f < 4; ++f) {
        af[f] = *(const s16x8*)&As[wm * 64 + f * 16 + l15][gl * 8 + kd * 32];
        bf[f] = *(const s16x8*)&Bs[wn * 64 + f * 16 + l15][gl * 8 + kd * 32];
      }
#pragma unroll
      for (int fm = 0; fm < 4; ++fm)
#pragma unroll
        for (int fn = 0; fn < 4; ++fn)
          acc[fm][fn] = __builtin_amdgcn_mfma_f32_16x16x32_bf16(
              af[fm], bf[fn], acc[fm][fn], 0, 0, 0);
    }
  }

#pragma unroll
  for (int fn = 0; fn < 4; ++fn) {
    const int n = n0 + wn * 64 + fn * 16 + l15;
    const float bn = (EPI == 0) ? bias[n] : 0.f;
#pragma unroll
    for (int fm = 0; fm < 4; ++fm) {
#pragma unroll
      for (int r = 0; r < 4; ++r) {
        const int m = m0 + wm * 64 + fm * 16 + gl * 4 + r;
        if (EPI == 0) {
          Cb[(size_t)m * DM + n] = f2b((acc[fm][fn][r] + bn) * outscale);
        } else {
          const int brow = m >> 9;
          float z = acc[fm][fn][r] + GB[brow * DM + n];
          float g = 1.f / (1.f + __expf(-z));
          float lo = b2f(A[(size_t)m * DM + n]);
          Cf[(size_t)m * DM + n] = g * lo + (1.f - g) * GO[brow * DM + n];
        }
      }
    }
  }
}

// ---------------------------------------------------------------------------
// MFMA block-local flash attention. grid (64 g, 8 h), 512 threads = 8 waves.
// Wave w handles queries [w*64, w*64+64) of token-block g, head h.
// S^T = mfma(K, Q) per 64-key chunk; softmax in-register (online);
// P routed through per-wave LDS; O += mfma(P, V) with V^T-staged LDS.
// CTX may alias Q (reads complete before writes, disjoint rows/cols per block).
// ---------------------------------------------------------------------------
__global__ __launch_bounds__(512, 2)
void attn_mfma(const u16* Q, const u16* __restrict__ K,
               const u16* __restrict__ V, u16* CTX)
{
  __shared__ u16 Ks[64][72];      // [key][d]
  __shared__ u16 VsT[64][72];     // [d][key]
  __shared__ u16 Ps[8][64][72];   // per wave: [q][key]
  const int tid = threadIdx.x;
  const int w = tid >> 6, l = tid & 63;
  const int l15 = l & 15, gl = l >> 4;
  const int g = blockIdx.x, h = blockIdx.y;
  const int t0 = g * 512;
  const int fb = h * 64;

  // Q fragments: qf[fq][kd] = Q[t0 + w*64 + fq*16 + l15][fb + gl*8 + kd*32 ..+8]
  s16x8 qf[4][2];
#pragma unroll
  for (int fq = 0; fq < 4; ++fq)
#pragma unroll
    for (int kd = 0; kd < 2; ++kd)
      qf[fq][kd] = *(const s16x8*)(Q + (size_t)(t0 + w * 64 + fq * 16 + l15) * DM
                                     + fb + gl * 8 + kd * 32);

  f32x4 o[4][4];                  // o[qm][fd]
#pragma unroll
  for (int i = 0; i < 4; ++i)
#pragma unroll
    for (int j = 0; j < 4; ++j) o[i][j] = {0.f, 0.f, 0.f, 0.f};
  float m_[4] = {-INFINITY, -INFINITY, -INFINITY, -INFINITY};
  float l_[4] = {0.f, 0.f, 0.f, 0.f};

  for (int kc = 0; kc < 8; ++kc) {
    __syncthreads();
    {
      // stage K chunk [64][64] and V^T chunk [64][64]; one 16B piece per thread
      const int row = tid >> 3, d0 = (tid & 7) * 8;
      const size_t goff = (size_t)(t0 + kc * 64 + row) * DM + fb + d0;
      *(s16x8*)&Ks[row][d0] = *(const s16x8*)(K + goff);
      u16x8 vv = *(const u16x8*)(V + goff);
#pragma unroll
      for (int j = 0; j < 8; ++j) VsT[d0 + j][row] = vv[j];
    }
    __syncthreads();

    // S^T = K @ Q^T : s[fm][fq], C row = key = fm*16+gl*4+r, col = q = fq*16+l15
    f32x4 s[4][4];
#pragma unroll
    for (int i = 0; i < 4; ++i)
#pragma unroll
      for (int j = 0; j < 4; ++j) s[i][j] = {0.f, 0.f, 0.f, 0.f};
#pragma unroll
    for (int kd = 0; kd < 2; ++kd) {
      s16x8 kf[4];
#pragma unroll
      for (int fm = 0; fm < 4; ++fm)
        kf[fm] = *(const s16x8*)&Ks[fm * 16 + l15][gl * 8 + kd * 32];
#pragma unroll
      for (int fm = 0; fm < 4; ++fm)
#pragma unroll
        for (int fq = 0; fq < 4; ++fq)
          s[fm][fq] = __builtin_amdgcn_mfma_f32_16x16x32_bf16(
              kf[fm], qf[fq][kd], s[fm][fq], 0, 0, 0);
    }

    // online softmax per query column (q = fq*16 + l15)
    float alpha[4];
#pragma unroll
    for (int fq = 0; fq < 4; ++fq) {
      float cm = s[0][fq][0];
#pragma unroll
      for (int fm = 0; fm < 4; ++fm)
#pragma unroll
        for (int r = 0; r < 4; ++r) cm = fmaxf(cm, s[fm][fq][r]);
      cm = fmaxf(cm, __shfl_xor(cm, 16));
      cm = fmaxf(cm, __shfl_xor(cm, 32));
      const float mnew = fmaxf(m_[fq], cm);
      alpha[fq] = __expf(m_[fq] - mnew);   // 0 on first chunk (-inf - finite)
      m_[fq] = mnew;
      float psum = 0.f;
#pragma unroll
      for (int fm = 0; fm < 4; ++fm) {
        float p0 = __expf(s[fm][fq][0] - mnew);
        float p1 = __expf(s[fm][fq][1] - mnew);
        float p2 = __expf(s[fm][fq][2] - mnew);
        float p3 = __expf(s[fm][fq][3] - mnew);
        psum += (p0 + p1) + (p2 + p3);
        unsigned pk01 = (unsigned)f2b(p0) | ((unsigned)f2b(p1) << 16);
        unsigned pk23 = (unsigned)f2b(p2) | ((unsigned)f2b(p3) << 16);
        // P[q][key]: key = fm*16 + gl*4 + {0..3}
        *(unsigned*)&Ps[w][fq * 16 + l15][fm * 16 + gl * 4]     = pk01;
        *(unsigned*)&Ps[w][fq * 16 + l15][fm * 16 + gl * 4 + 2] = pk23;
      }
      psum += __shfl_xor(psum, 16);
      psum += __shfl_xor(psum, 32);
      l_[fq] = l_[fq] * alpha[fq] + psum;
    }

    // rescale O by alpha (per output row q = qm*16 + gl*4 + r)
#pragma unroll
    for (int qm = 0; qm < 4; ++qm) {
      float a0 = __shfl(alpha[qm], gl * 4 + 0);
      float a1 = __shfl(alpha[qm], gl * 4 + 1);
      float a2 = __shfl(alpha[qm], gl * 4 + 2);
      float a3 = __shfl(alpha[qm], gl * 4 + 3);
#pragma unroll
      for (int fd = 0; fd < 4; ++fd) {
        o[qm][fd][0] *= a0; o[qm][fd][1] *= a1;
        o[qm][fd][2] *= a2; o[qm][fd][3] *= a3;
      }
    }

    // O += P @ V
#pragma unroll
    for (int ka = 0; ka < 2; ++ka) {
      s16x8 pf[4], vf[4];
#pragma unroll
      for (int qm = 0; qm < 4; ++qm)
        pf[qm] = *(const s16x8*)&Ps[w][qm * 16 + l15][gl * 8 + ka * 32];
#pragma unroll
      for (int fd = 0; fd < 4; ++fd)
        vf[fd] = *(const s16x8*)&VsT[fd * 16 + l15][gl * 8 + ka * 32];
#pragma unroll
      for (int qm = 0; qm < 4; ++qm)
#pragma unroll
        for (int fd = 0; fd < 4; ++fd)
          o[qm][fd] = __builtin_amdgcn_mfma_f32_16x16x32_bf16(
              pf[qm], vf[fd], o[qm][fd], 0, 0, 0);
    }
  }

  // normalize and store
#pragma unroll
  for (int qm = 0; qm < 4; ++qm) {
    float i0 = 1.f / __shfl(l_[qm], gl * 4 + 0);
    float i1 = 1.f / __shfl(l_[qm], gl * 4 + 1);
    float i2 = 1.f / __shfl(l_[qm], gl * 4 + 2);
    float i3 = 1.f / __shfl(l_[qm], gl * 4 + 3);
#pragma unroll
    for (int fd = 0; fd < 4; ++fd) {
      const size_t base = (size_t)(t0 + w * 64 + qm * 16 + gl * 4) * DM
                          + fb + fd * 16 + l15;
      CTX[base]           = f2b(o[qm][fd][0] * i0);
      CTX[base + DM]      = f2b(o[qm][fd][1] * i1);
      CTX[base + 2 * DM]  = f2b(o[qm][fd][2] * i2);
      CTX[base + 3 * DM]  = f2b(o[qm][fd][3] * i3);
    }
  }
}

// ---------------------------------------------------------------------------
// Pooled block means: P[64][512] = mean over 512 tokens of x (fp32)
// ---------------------------------------------------------------------------
__global__ __launch_bounds__(256)
void pool_mean(const float* __restrict__ X, float* __restrict__ P)
{
  const int g = blockIdx.x;
  const int tid = threadIdx.x;
  const float* xp = X + (size_t)g * 512 * DM;
  float a0 = 0.f, a1 = 0.f;
  for (int t = 0; t < 512; ++t) {
    a0 += xp[t * DM + tid];
    a1 += xp[t * DM + tid + 256];
  }
  P[g * DM + tid]       = a0 * (1.f / 512.f);
  P[g * DM + tid + 256] = a1 * (1.f / 512.f);
}

// ---------------------------------------------------------------------------
// Small GEMM: Out[64 x 512] = A[64 x 512] @ W[512 x 512] + bias (all fp32)
// ---------------------------------------------------------------------------
__global__ __launch_bounds__(256)
void small_gemm(const float* __restrict__ A, const float* __restrict__ W,
                const float* __restrict__ bias, float* __restrict__ Out)
{
  __shared__ float a[512];
  const int r = blockIdx.x;
  const int tid = threadIdx.x;
  a[tid]       = A[(size_t)r * DM + tid];
  a[tid + 256] = A[(size_t)r * DM + tid + 256];
  __syncthreads();
  float acc0 = 0.f, acc1 = 0.f;
  for (int k = 0; k < DM; ++k) {
    const float av = a[k];
    acc0 = fmaf(av, W[(size_t)k * DM + tid],       acc0);
    acc1 = fmaf(av, W[(size_t)k * DM + tid + 256], acc1);
  }
  Out[(size_t)r * DM + tid]       = acc0 + bias[tid];
  Out[(size_t)r * DM + tid + 256] = acc1 + bias[tid + 256];
}

// ---------------------------------------------------------------------------
// Global attention over 16 pooled summaries per batch. grid 32: (b, h). fp32.
// ---------------------------------------------------------------------------
__global__ __launch_bounds__(256)
void gattn(const float* __restrict__ Qg, const float* __restrict__ Kg,
           const float* __restrict__ Vg, float* __restrict__ Gl)
{
  __shared__ float q[16][64], k[16][64], v[16][64];
  __shared__ float sc[16][16];
  const int bh = blockIdx.x;
  const int b = bh >> 3, h = bh & 7;
  const int tid = threadIdx.x;
  for (int idx = tid; idx < 1024; idx += 256) {
    const int n = idx >> 6, d = idx & 63;
    const size_t off = (size_t)(b * 16 + n) * DM + h * 64 + d;
    q[n][d] = Qg[off]; k[n][d] = Kg[off]; v[n][d] = Vg[off];
  }
  __syncthreads();
  {
    const int qq = tid >> 4, kk = tid & 15;
    float s = 0.f;
#pragma unroll
    for (int d = 0; d < 64; ++d) s = fmaf(q[qq][d], k[kk][d], s);
    sc[qq][kk] = s * SCALE;
  }
  __syncthreads();
  if (tid < 16) {
    float mx = -INFINITY;
#pragma unroll
    for (int j = 0; j < 16; ++j) mx = fmaxf(mx, sc[tid][j]);
    float e[16]; float sum = 0.f;
#pragma unroll
    for (int j = 0; j < 16; ++j) { e[j] = __expf(sc[tid][j] - mx); sum += e[j]; }
    const float inv = 1.f / sum;
#pragma unroll
    for (int j = 0; j < 16; ++j) sc[tid][j] = e[j] * inv;
  }
  __syncthreads();
  for (int idx = tid; idx < 1024; idx += 256) {
    const int qq = idx >> 6, d = idx & 63;
    float o = 0.f;
#pragma unroll
    for (int j = 0; j < 16; ++j) o = fmaf(sc[qq][j], v[j][d], o);
    Gl[(size_t)(b * 16 + qq) * DM + h * 64 + d] = o;
  }
}

// ---------------------------------------------------------------------------
extern "C" void kernel_launch(void* const* d_in, const int* in_sizes, int n_in,
                              void* d_out, int out_size, void* d_ws, size_t ws_size,
                              hipStream_t stream)
{
  const float* x      = (const float*)d_in[0];
  const float* lq_w   = (const float*)d_in[1];
  const float* lq_b   = (const float*)d_in[2];
  const float* lk_w   = (const float*)d_in[3];
  const float* lk_b   = (const float*)d_in[4];
  const float* lv_w   = (const float*)d_in[5];
  const float* lv_b   = (const float*)d_in[6];
  const float* lo_w   = (const float*)d_in[7];
  const float* lo_b   = (const float*)d_in[8];
  const float* gq_w   = (const float*)d_in[9];
  const float* gq_b   = (const float*)d_in[10];
  const float* gk_w   = (const float*)d_in[11];
  const float* gk_b   = (const float*)d_in[12];
  const float* gv_w   = (const float*)d_in[13];
  const float* gv_b   = (const float*)d_in[14];
  const float* go_w   = (const float*)d_in[15];
  const float* go_b   = (const float*)d_in[16];
  const float* gate_w = (const float*)d_in[17];
  const float* gate_b = (const float*)d_in[18];
  float* out = (float*)d_out;

  const size_t NE = (size_t)NTOK * DM;       // 16.7M elems
  char* ws = (char*)d_ws;
  u16* Qb = (u16*)ws;                        // 32 MiB; CTX aliases Qb
  u16* Kb = Qb + NE;                         // 32 MiB
  u16* Vb = Kb + NE;                         // 32 MiB; LOCAL aliases Vb
  u16* WT = Vb + NE;                         // 5 x 512x512 bf16 = 2.5 MiB
  float* scr     = (float*)(WT + (size_t)5 * DM * DM);
  float* pooled  = scr;                      // 7 x 32768 fp32
  float* Qg      = pooled + 32768;
  float* Kg      = Qg + 32768;
  float* Vg      = Kg + 32768;
  float* Gl      = Vg + 32768;
  float* GOUT    = Gl + 32768;
  float* GATEBLK = GOUT + 32768;
  // x in bf16 lives in the (otherwise dead until the last GEMM) output buffer
  u16* xb = (u16*)d_out;

  conv_x<<<NE / (256 * 8), 256, 0, stream>>>(x, xb);
  trans_w<<<dim3(16, 16, 5), 256, 0, stream>>>(lq_w, lk_w, lv_w, lo_w, gate_w, WT);

  const dim3 gg(4, 256), bb(256);
  u16* WTq = WT;
  u16* WTk = WT + (size_t)1 * DM * DM;
  u16* WTv = WT + (size_t)2 * DM * DM;
  u16* WTo = WT + (size_t)3 * DM * DM;
  u16* WTg = WT + (size_t)4 * DM * DM;
  gemm_mfma<0><<<gg, bb, 0, stream>>>(xb, WTq, lq_b, Qb, nullptr, SCALE, nullptr, nullptr);
  gemm_mfma<0><<<gg, bb, 0, stream>>>(xb, WTk, lk_b, Kb, nullptr, 1.0f, nullptr, nullptr);
  gemm_mfma<0><<<gg, bb, 0, stream>>>(xb, WTv, lv_b, Vb, nullptr, 1.0f, nullptr, nullptr);
  attn_mfma<<<dim3(64, 8), 512, 0, stream>>>(Qb, Kb, Vb, Qb /*CTX in place*/);
  gemm_mfma<0><<<gg, bb, 0, stream>>>(Qb /*CTX*/, WTo, lo_b, Vb /*LOCAL*/, nullptr, 1.0f, nullptr, nullptr);

  pool_mean<<<64, 256, 0, stream>>>(x, pooled);
  small_gemm<<<64, 256, 0, stream>>>(pooled, gq_w, gq_b, Qg);
  small_gemm<<<64, 256, 0, stream>>>(pooled, gk_w, gk_b, Kg);
  small_gemm<<<64, 256, 0, stream>>>(pooled, gv_w, gv_b, Vg);
  gattn<<<32, 256, 0, stream>>>(Qg, Kg, Vg, Gl);
  small_gemm<<<64, 256, 0, stream>>>(Gl, go_w, go_b, GOUT);
  small_gemm<<<64, 256, 0, stream>>>(GOUT, gate_w + (size_t)DM * DM, gate_b, GATEBLK);

  gemm_mfma<1><<<gg, bb, 0, stream>>>(Vb /*LOCAL*/, WTg, nullptr, nullptr, out, 1.0f, GATEBLK, GOUT);
}

// Round 4
// 346.948 us; speedup vs baseline: 6.4070x; 1.2174x over previous
//
#include <hip/hip_runtime.h>
#include <math.h>

typedef unsigned short u16;
typedef short s16;
typedef u16 u16x8 __attribute__((ext_vector_type(8)));
typedef u16 u16x4 __attribute__((ext_vector_type(4)));
typedef s16 s16x8 __attribute__((ext_vector_type(8)));
typedef float f32x4 __attribute__((ext_vector_type(4)));

__device__ __forceinline__ float b2f(u16 u) { return __uint_as_float(((unsigned)u) << 16); }
__device__ __forceinline__ u16 f2b(float f) {
  unsigned x = __float_as_uint(f);
  unsigned r = x + 0x7fffu + ((x >> 16) & 1u);
  return (u16)(r >> 16);
}

#define SCALE 0.125f
#define DM 512
#define NTOK 32768

// ---------------------------------------------------------------------------
// global -> LDS direct copy, 16 B/lane (wave-uniform LDS base + lane*16)
// ---------------------------------------------------------------------------
typedef __attribute__((address_space(1))) unsigned int as1_u32;
typedef __attribute__((address_space(3))) unsigned int as3_u32;
__device__ __forceinline__ void gl2lds16(const u16* g, u16* s) {
  __builtin_amdgcn_global_load_lds((as1_u32*)g, (as3_u32*)s, 16, 0, 0);
}

// ---------------------------------------------------------------------------
// x fp32 -> bf16 + per-64-token column partial sums (for pooled means)
// grid 512 (64 tokens each), block 256
// ---------------------------------------------------------------------------
__global__ __launch_bounds__(256)
void conv_psum(const float* __restrict__ X, u16* __restrict__ Xb,
               float* __restrict__ Psum)
{
  __shared__ float ps[4][512];
  const int tid = threadIdx.x;
  const int c8 = (tid & 63) * 8;
  const int rg = tid >> 6;
  const size_t tok0 = (size_t)blockIdx.x * 64;
  f32x4 s0 = {0.f, 0.f, 0.f, 0.f}, s1 = {0.f, 0.f, 0.f, 0.f};
  for (int it = 0; it < 16; ++it) {
    const size_t tok = tok0 + it * 4 + rg;
    const float* xp = X + tok * DM + c8;
    f32x4 a = *(const f32x4*)xp;
    f32x4 b = *(const f32x4*)(xp + 4);
    u16x8 o;
    o[0]=f2b(a[0]); o[1]=f2b(a[1]); o[2]=f2b(a[2]); o[3]=f2b(a[3]);
    o[4]=f2b(b[0]); o[5]=f2b(b[1]); o[6]=f2b(b[2]); o[7]=f2b(b[3]);
    *(u16x8*)(Xb + tok * DM + c8) = o;
    s0 += a; s1 += b;
  }
  *(f32x4*)&ps[rg][c8]     = s0;
  *(f32x4*)&ps[rg][c8 + 4] = s1;
  __syncthreads();
#pragma unroll
  for (int i = 0; i < 2; ++i) {
    const int col = tid + i * 256;
    Psum[(size_t)blockIdx.x * DM + col] =
        ps[0][col] + ps[1][col] + ps[2][col] + ps[3][col];
  }
}

// ---------------------------------------------------------------------------
// transpose-convert 5 weight matrices [512k][512n] fp32 -> Wt [512n][512k] bf16
// ---------------------------------------------------------------------------
__global__ __launch_bounds__(256)
void trans_w(const float* w0, const float* w1, const float* w2,
             const float* w3, const float* w4, u16* __restrict__ WT)
{
  __shared__ float t[32][33];
  const int z = blockIdx.z;
  const float* W = (z == 0) ? w0 : (z == 1) ? w1 : (z == 2) ? w2 : (z == 3) ? w3 : w4;
  u16* D = WT + (size_t)z * DM * DM;
  const int tx = threadIdx.x & 31, ty = threadIdx.x >> 5;
  const int n0 = blockIdx.x * 32, k0 = blockIdx.y * 32;
#pragma unroll
  for (int j = 0; j < 4; ++j)
    t[ty + j * 8][tx] = W[(size_t)(k0 + ty + j * 8) * DM + n0 + tx];
  __syncthreads();
#pragma unroll
  for (int j = 0; j < 4; ++j)
    D[(size_t)(n0 + ty + j * 8) * DM + k0 + tx] = f2b(t[tx][ty + j * 8]);
}

// ---------------------------------------------------------------------------
// MFMA GEMM (m97 structure): 128x128 tile, BK=64, global_load_lds staging,
// linear LDS [128][64]. 256 threads = 4 waves (2x2), 64x64 per wave.
// EPI 0: Cb[m][n] = bf16((acc + bias[n]) * outscale)   (row-major)
// EPI 1: z = acc + GB[brow][n]; g = sigmoid(z); Cf = g*A[m][n] + (1-g)*GO[brow][n]
// EPI 2: VT[((m>>9)*8 + (n>>6))*64 + (n&63)][m&511] = bf16(acc + bias[n])
// ---------------------------------------------------------------------------
template<int EPI>
__global__ __launch_bounds__(256)
void gemm_mfma(const u16* __restrict__ A, const u16* __restrict__ Wt,
               const float* __restrict__ bias, u16* __restrict__ Cb,
               float* __restrict__ Cf, float outscale,
               const float* __restrict__ GB, const float* __restrict__ GO)
{
  __shared__ u16 As[128 * 64];
  __shared__ u16 Bs[128 * 64];
  const int tid = threadIdx.x;
  const int w = tid >> 6, l = tid & 63;
  const int l15 = l & 15, gl = l >> 4;
  const int wm = w >> 1, wn = w & 1;
  const int m0 = blockIdx.y * 128, n0 = blockIdx.x * 128;

  // wave w stages rows [w*32, w*32+32): 4 chunks of 8 rows, 16 B/lane
  const int srow = l >> 3;
  const int scol = (l & 7) * 8;
  const u16* Ag = A  + (size_t)(m0 + w * 32 + srow) * DM + scol;
  const u16* Bg = Wt + (size_t)(n0 + w * 32 + srow) * DM + scol;

  f32x4 acc[4][4];
#pragma unroll
  for (int i = 0; i < 4; ++i)
#pragma unroll
    for (int j = 0; j < 4; ++j) acc[i][j] = {0.f, 0.f, 0.f, 0.f};

  for (int k0 = 0; k0 < DM; k0 += 64) {
    __syncthreads();
#pragma unroll
    for (int c = 0; c < 4; ++c) {
      gl2lds16(Ag + (size_t)(c * 8) * DM + k0, As + (w * 32 + c * 8) * 64);
      gl2lds16(Bg + (size_t)(c * 8) * DM + k0, Bs + (w * 32 + c * 8) * 64);
    }
    __syncthreads();
#pragma unroll
    for (int kd = 0; kd < 2; ++kd) {
      s16x8 af[4], bf[4];
#pragma unroll
      for (int f = 0; f < 4; ++f) {
        af[f] = *(const s16x8*)&As[(wm * 64 + f * 16 + l15) * 64 + gl * 8 + kd * 32];
        bf[f] = *(const s16x8*)&Bs[(wn * 64 + f * 16 + l15) * 64 + gl * 8 + kd * 32];
      }
#pragma unroll
      for (int fm = 0; fm < 4; ++fm)
#pragma unroll
        for (int fn = 0; fn < 4; ++fn)
          acc[fm][fn] = __builtin_amdgcn_mfma_f32_16x16x32_bf16(
              af[fm], bf[fn], acc[fm][fn], 0, 0, 0);
    }
  }

#pragma unroll
  for (int fn = 0; fn < 4; ++fn) {
    const int n = n0 + wn * 64 + fn * 16 + l15;
    const float bn = (EPI == 1) ? 0.f : bias[n];
#pragma unroll
    for (int fm = 0; fm < 4; ++fm) {
      if (EPI == 2) {
        const int m = m0 + wm * 64 + fm * 16 + gl * 4;
        const int gh = (m >> 9) * 8 + (n >> 6);
        u16x4 p;
#pragma unroll
        for (int r = 0; r < 4; ++r) p[r] = f2b(acc[fm][fn][r] + bn);
        *(u16x4*)(Cb + ((size_t)gh * 64 + (n & 63)) * 512 + (m & 511)) = p;
      } else {
#pragma unroll
        for (int r = 0; r < 4; ++r) {
          const int m = m0 + wm * 64 + fm * 16 + gl * 4 + r;
          if (EPI == 0) {
            Cb[(size_t)m * DM + n] = f2b((acc[fm][fn][r] + bn) * outscale);
          } else {
            const int brow = m >> 9;
            float z = acc[fm][fn][r] + GB[brow * DM + n];
            float gg = 1.f / (1.f + __expf(-z));
            float lo = b2f(A[(size_t)m * DM + n]);
            Cf[(size_t)m * DM + n] = gg * lo + (1.f - gg) * GO[brow * DM + n];
          }
        }
      }
    }
  }
}

// ---------------------------------------------------------------------------
// MFMA flash attention, register-resident P (no P LDS round-trip).
// grid (64 g, 8 h, 2 qh), 512 threads = 8 waves, 32 queries per wave.
// S^T = mfma(K, Q): lane holds P[key=fm*16+gl*4+r][q=fq*16+l15].
// PV feeds A directly from these registers with key-map
// K(ka,gl,j) = (2ka+(j>>2))*16 + gl*4 + (j&3), and gathers V^T (from VT)
// in the SAME key order -> contraction correct for any bijective key map.
// CTX aliases Q (wave reads exactly the rows it later writes).
// ---------------------------------------------------------------------------
__global__ __launch_bounds__(512, 4)
void attn_mfma(const u16* __restrict__ Q, const u16* __restrict__ K,
               const u16* __restrict__ VT, u16* __restrict__ CTX)
{
  __shared__ u16 Ks[64][72];      // [key][d]
  __shared__ u16 VsT[64][72];     // [d][key]
  const int tid = threadIdx.x;
  const int w = tid >> 6, l = tid & 63;
  const int l15 = l & 15, gl = l >> 4;
  const int g = blockIdx.x, h = blockIdx.y, qh = blockIdx.z;
  const int t0 = g * 512;
  const int fb = h * 64;
  const int q0 = t0 + qh * 256 + w * 32;
  const u16* VTb = VT + ((size_t)(g * 8 + h) * 64) * 512;

  s16x8 qf[2][2];
#pragma unroll
  for (int fq = 0; fq < 2; ++fq)
#pragma unroll
    for (int kd = 0; kd < 2; ++kd)
      qf[fq][kd] = *(const s16x8*)(Q + (size_t)(q0 + fq * 16 + l15) * DM
                                     + fb + gl * 8 + kd * 32);

  f32x4 o[2][4];
#pragma unroll
  for (int i = 0; i < 2; ++i)
#pragma unroll
    for (int j = 0; j < 4; ++j) o[i][j] = {0.f, 0.f, 0.f, 0.f};
  float m_[2] = {-INFINITY, -INFINITY};
  float l_[2] = {0.f, 0.f};

  const int srow = tid >> 3, sd0 = (tid & 7) * 8;

  for (int kc = 0; kc < 8; ++kc) {
    __syncthreads();
    *(s16x8*)&Ks[srow][sd0]  = *(const s16x8*)(K + (size_t)(t0 + kc * 64 + srow) * DM + fb + sd0);
    *(s16x8*)&VsT[srow][sd0] = *(const s16x8*)(VTb + (size_t)srow * 512 + kc * 64 + sd0);
    __syncthreads();

    // S^T = K @ Q^T
    f32x4 s[4][2];
#pragma unroll
    for (int i = 0; i < 4; ++i)
#pragma unroll
      for (int j = 0; j < 2; ++j) s[i][j] = {0.f, 0.f, 0.f, 0.f};
#pragma unroll
    for (int kd = 0; kd < 2; ++kd) {
      s16x8 kf[4];
#pragma unroll
      for (int fm = 0; fm < 4; ++fm)
        kf[fm] = *(const s16x8*)&Ks[fm * 16 + l15][gl * 8 + kd * 32];
#pragma unroll
      for (int fm = 0; fm < 4; ++fm)
#pragma unroll
        for (int fq = 0; fq < 2; ++fq)
          s[fm][fq] = __builtin_amdgcn_mfma_f32_16x16x32_bf16(
              kf[fm], qf[fq][kd], s[fm][fq], 0, 0, 0);
    }

    // online softmax (per query column q = fq*16 + l15)
    float alpha[2];
#pragma unroll
    for (int fq = 0; fq < 2; ++fq) {
      float cm = -INFINITY;
#pragma unroll
      for (int fm = 0; fm < 4; ++fm)
#pragma unroll
        for (int r = 0; r < 4; ++r) cm = fmaxf(cm, s[fm][fq][r]);
      cm = fmaxf(cm, __shfl_xor(cm, 16));
      cm = fmaxf(cm, __shfl_xor(cm, 32));
      const float mnew = fmaxf(m_[fq], cm);
      alpha[fq] = __expf(m_[fq] - mnew);
      m_[fq] = mnew;
      float psum = 0.f;
#pragma unroll
      for (int fm = 0; fm < 4; ++fm)
#pragma unroll
        for (int r = 0; r < 4; ++r) {
          const float p = __expf(s[fm][fq][r] - mnew);
          s[fm][fq][r] = p;
          psum += p;
        }
      psum += __shfl_xor(psum, 16);
      psum += __shfl_xor(psum, 32);
      l_[fq] = l_[fq] * alpha[fq] + psum;
    }

    // pack P -> bf16 A-fragments, key-map K(ka,gl,j)
    s16x8 pf[2][2];
#pragma unroll
    for (int ka = 0; ka < 2; ++ka)
#pragma unroll
      for (int fq = 0; fq < 2; ++fq) {
        s16x8 t;
#pragma unroll
        for (int j = 0; j < 4; ++j) {
          t[j]     = (s16)f2b(s[2 * ka][fq][j]);
          t[j + 4] = (s16)f2b(s[2 * ka + 1][fq][j]);
        }
        pf[ka][fq] = t;
      }

    // rescale O rows (q = qm*16 + gl*4 + r)
#pragma unroll
    for (int qm = 0; qm < 2; ++qm) {
      const float a0 = __shfl(alpha[qm], gl * 4 + 0);
      const float a1 = __shfl(alpha[qm], gl * 4 + 1);
      const float a2 = __shfl(alpha[qm], gl * 4 + 2);
      const float a3 = __shfl(alpha[qm], gl * 4 + 3);
#pragma unroll
      for (int fd = 0; fd < 4; ++fd) {
        o[qm][fd][0] *= a0; o[qm][fd][1] *= a1;
        o[qm][fd][2] *= a2; o[qm][fd][3] *= a3;
      }
    }

    // O += P @ V  (B gathered in the same key order)
#pragma unroll
    for (int ka = 0; ka < 2; ++ka)
#pragma unroll
      for (int fd = 0; fd < 4; ++fd) {
        u16x4 v0 = *(const u16x4*)&VsT[fd * 16 + l15][ka * 32 + gl * 4];
        u16x4 v1 = *(const u16x4*)&VsT[fd * 16 + l15][ka * 32 + 16 + gl * 4];
        s16x8 vf;
        vf[0]=(s16)v0[0]; vf[1]=(s16)v0[1]; vf[2]=(s16)v0[2]; vf[3]=(s16)v0[3];
        vf[4]=(s16)v1[0]; vf[5]=(s16)v1[1]; vf[6]=(s16)v1[2]; vf[7]=(s16)v1[3];
#pragma unroll
        for (int qm = 0; qm < 2; ++qm)
          o[qm][fd] = __builtin_amdgcn_mfma_f32_16x16x32_bf16(
              pf[ka][qm], vf, o[qm][fd], 0, 0, 0);
      }
  }

  // normalize and store
#pragma unroll
  for (int qm = 0; qm < 2; ++qm) {
    const float i0 = 1.f / __shfl(l_[qm], gl * 4 + 0);
    const float i1 = 1.f / __shfl(l_[qm], gl * 4 + 1);
    const float i2 = 1.f / __shfl(l_[qm], gl * 4 + 2);
    const float i3 = 1.f / __shfl(l_[qm], gl * 4 + 3);
#pragma unroll
    for (int fd = 0; fd < 4; ++fd) {
      const size_t base = (size_t)(q0 + qm * 16 + gl * 4) * DM + fb + fd * 16 + l15;
      CTX[base]          = f2b(o[qm][fd][0] * i0);
      CTX[base + DM]     = f2b(o[qm][fd][1] * i1);
      CTX[base + 2 * DM] = f2b(o[qm][fd][2] * i2);
      CTX[base + 3 * DM] = f2b(o[qm][fd][3] * i3);
    }
  }
}

// ---------------------------------------------------------------------------
// pooled means (from Psum) -> Qg/Kg/Vg small GEMMs. grid (64, 3).
// ---------------------------------------------------------------------------
__global__ __launch_bounds__(256)
void small_qkv(const float* __restrict__ Psum,
               const float* __restrict__ Wq, const float* __restrict__ bq,
               const float* __restrict__ Wk, const float* __restrict__ bk,
               const float* __restrict__ Wv, const float* __restrict__ bv,
               float* __restrict__ Qg, float* __restrict__ Kg, float* __restrict__ Vg)
{
  __shared__ float a[512];
  const int g = blockIdx.x, z = blockIdx.y;
  const int tid = threadIdx.x;
  const float* W = (z == 0) ? Wq : (z == 1) ? Wk : Wv;
  const float* b = (z == 0) ? bq : (z == 1) ? bk : bv;
  float* Out     = (z == 0) ? Qg : (z == 1) ? Kg : Vg;
#pragma unroll
  for (int i = 0; i < 2; ++i) {
    const int col = tid + i * 256;
    float v = 0.f;
#pragma unroll
    for (int s = 0; s < 8; ++s) v += Psum[(size_t)(g * 8 + s) * DM + col];
    a[col] = v * (1.f / 512.f);
  }
  __syncthreads();
  float acc0 = 0.f, acc1 = 0.f;
  for (int k = 0; k < DM; ++k) {
    const float av = a[k];
    acc0 = fmaf(av, W[(size_t)k * DM + tid],       acc0);
    acc1 = fmaf(av, W[(size_t)k * DM + tid + 256], acc1);
  }
  Out[(size_t)g * DM + tid]       = acc0 + b[tid];
  Out[(size_t)g * DM + tid + 256] = acc1 + b[tid + 256];
}

// ---------------------------------------------------------------------------
// Global attention over 16 pooled summaries per batch. grid 32: (b, h). fp32.
// ---------------------------------------------------------------------------
__global__ __launch_bounds__(256)
void gattn(const float* __restrict__ Qg, const float* __restrict__ Kg,
           const float* __restrict__ Vg, float* __restrict__ Gl)
{
  __shared__ float q[16][64], k[16][64], v[16][64];
  __shared__ float sc[16][16];
  const int bh = blockIdx.x;
  const int b = bh >> 3, h = bh & 7;
  const int tid = threadIdx.x;
  for (int idx = tid; idx < 1024; idx += 256) {
    const int n = idx >> 6, d = idx & 63;
    const size_t off = (size_t)(b * 16 + n) * DM + h * 64 + d;
    q[n][d] = Qg[off]; k[n][d] = Kg[off]; v[n][d] = Vg[off];
  }
  __syncthreads();
  {
    const int qq = tid >> 4, kk = tid & 15;
    float s = 0.f;
#pragma unroll
    for (int d = 0; d < 64; ++d) s = fmaf(q[qq][d], k[kk][d], s);
    sc[qq][kk] = s * SCALE;
  }
  __syncthreads();
  if (tid < 16) {
    float mx = -INFINITY;
#pragma unroll
    for (int j = 0; j < 16; ++j) mx = fmaxf(mx, sc[tid][j]);
    float e[16]; float sum = 0.f;
#pragma unroll
    for (int j = 0; j < 16; ++j) { e[j] = __expf(sc[tid][j] - mx); sum += e[j]; }
    const float inv = 1.f / sum;
#pragma unroll
    for (int j = 0; j < 16; ++j) sc[tid][j] = e[j] * inv;
  }
  __syncthreads();
  for (int idx = tid; idx < 1024; idx += 256) {
    const int qq = idx >> 6, d = idx & 63;
    float o = 0.f;
#pragma unroll
    for (int j = 0; j < 16; ++j) o = fmaf(sc[qq][j], v[j][d], o);
    Gl[(size_t)(b * 16 + qq) * DM + h * 64 + d] = o;
  }
}

// ---------------------------------------------------------------------------
// GOUT[r] = Gl[r] @ go_w + go_b ; GATEBLK[r] = GOUT[r] @ gate_w2 + gate_b
// ---------------------------------------------------------------------------
__global__ __launch_bounds__(256)
void go_gate(const float* __restrict__ Gl,
             const float* __restrict__ go_w, const float* __restrict__ go_b,
             const float* __restrict__ gw2, const float* __restrict__ gate_b,
             float* __restrict__ GOUT, float* __restrict__ GATEBLK)
{
  __shared__ float a[512];
  const int r = blockIdx.x, tid = threadIdx.x;
  a[tid]       = Gl[(size_t)r * DM + tid];
  a[tid + 256] = Gl[(size_t)r * DM + tid + 256];
  __syncthreads();
  float acc0 = 0.f, acc1 = 0.f;
  for (int k = 0; k < DM; ++k) {
    const float av = a[k];
    acc0 = fmaf(av, go_w[(size_t)k * DM + tid],       acc0);
    acc1 = fmaf(av, go_w[(size_t)k * DM + tid + 256], acc1);
  }
  acc0 += go_b[tid]; acc1 += go_b[tid + 256];
  GOUT[(size_t)r * DM + tid]       = acc0;
  GOUT[(size_t)r * DM + tid + 256] = acc1;
  __syncthreads();
  a[tid] = acc0; a[tid + 256] = acc1;
  __syncthreads();
  float g0 = 0.f, g1 = 0.f;
  for (int k = 0; k < DM; ++k) {
    const float av = a[k];
    g0 = fmaf(av, gw2[(size_t)k * DM + tid],       g0);
    g1 = fmaf(av, gw2[(size_t)k * DM + tid + 256], g1);
  }
  GATEBLK[(size_t)r * DM + tid]       = g0 + gate_b[tid];
  GATEBLK[(size_t)r * DM + tid + 256] = g1 + gate_b[tid + 256];
}

// ---------------------------------------------------------------------------
extern "C" void kernel_launch(void* const* d_in, const int* in_sizes, int n_in,
                              void* d_out, int out_size, void* d_ws, size_t ws_size,
                              hipStream_t stream)
{
  const float* x      = (const float*)d_in[0];
  const float* lq_w   = (const float*)d_in[1];
  const float* lq_b   = (const float*)d_in[2];
  const float* lk_w   = (const float*)d_in[3];
  const float* lk_b   = (const float*)d_in[4];
  const float* lv_w   = (const float*)d_in[5];
  const float* lv_b   = (const float*)d_in[6];
  const float* lo_w   = (const float*)d_in[7];
  const float* lo_b   = (const float*)d_in[8];
  const float* gq_w   = (const float*)d_in[9];
  const float* gq_b   = (const float*)d_in[10];
  const float* gk_w   = (const float*)d_in[11];
  const float* gk_b   = (const float*)d_in[12];
  const float* gv_w   = (const float*)d_in[13];
  const float* gv_b   = (const float*)d_in[14];
  const float* go_w   = (const float*)d_in[15];
  const float* go_b   = (const float*)d_in[16];
  const float* gate_w = (const float*)d_in[17];
  const float* gate_b = (const float*)d_in[18];
  float* out = (float*)d_out;

  const size_t NE = (size_t)NTOK * DM;
  char* ws = (char*)d_ws;
  u16* Qb = (u16*)ws;                    // 32 MiB; CTX aliases (safe: per-wave
  u16* Kb = Qb + NE;                     //   rows read-before-write)
  u16* VT = Kb + NE;                     // 32 MiB, V pre-transposed per (g,h)
  u16* WT = VT + NE;                     // 5 x 512x512 bf16
  float* scr     = (float*)(WT + (size_t)5 * DM * DM);
  float* Psum    = scr;                  // 512 x 512 f32
  float* Qg      = Psum + 512 * DM;
  float* Kg      = Qg + 64 * DM;
  float* Vg      = Kg + 64 * DM;
  float* Gl      = Vg + 64 * DM;
  float* GOUT    = Gl + 64 * DM;
  float* GATEBLK = GOUT + 64 * DM;
  u16* xb = (u16*)d_out;                 // bf16 x lives in d_out until final GEMM
  u16* LOCAL = Kb;                       // Kb dead after attention

  u16* WTq = WT;
  u16* WTk = WT + (size_t)1 * DM * DM;
  u16* WTv = WT + (size_t)2 * DM * DM;
  u16* WTo = WT + (size_t)3 * DM * DM;
  u16* WTg = WT + (size_t)4 * DM * DM;

  conv_psum<<<512, 256, 0, stream>>>(x, xb, Psum);
  trans_w<<<dim3(16, 16, 5), 256, 0, stream>>>(lq_w, lk_w, lv_w, lo_w, gate_w, WT);

  const dim3 gg(4, 256), bb(256);
  gemm_mfma<0><<<gg, bb, 0, stream>>>(xb, WTq, lq_b, Qb, nullptr, SCALE, nullptr, nullptr);
  gemm_mfma<0><<<gg, bb, 0, stream>>>(xb, WTk, lk_b, Kb, nullptr, 1.0f, nullptr, nullptr);
  gemm_mfma<2><<<gg, bb, 0, stream>>>(xb, WTv, lv_b, VT, nullptr, 1.0f, nullptr, nullptr);
  attn_mfma<<<dim3(64, 8, 2), 512, 0, stream>>>(Qb, Kb, VT, Qb /*CTX*/);
  gemm_mfma<0><<<gg, bb, 0, stream>>>(Qb /*CTX*/, WTo, lo_b, LOCAL, nullptr, 1.0f, nullptr, nullptr);

  small_qkv<<<dim3(64, 3), 256, 0, stream>>>(Psum, gq_w, gq_b, gk_w, gk_b, gv_w, gv_b, Qg, Kg, Vg);
  gattn<<<32, 256, 0, stream>>>(Qg, Kg, Vg, Gl);
  go_gate<<<64, 256, 0, stream>>>(Gl, go_w, go_b, gate_w + (size_t)DM * DM, gate_b, GOUT, GATEBLK);

  gemm_mfma<1><<<gg, bb, 0, stream>>>(LOCAL, WTg, nullptr, nullptr, out, 1.0f, GATEBLK, GOUT);
}

// Round 5
// 333.440 us; speedup vs baseline: 6.6665x; 1.0405x over previous
//
#include <hip/hip_runtime.h>
#include <math.h>

typedef unsigned short u16;
typedef short s16;
typedef u16 u16x8 __attribute__((ext_vector_type(8)));
typedef u16 u16x4 __attribute__((ext_vector_type(4)));
typedef s16 s16x8 __attribute__((ext_vector_type(8)));
typedef float f32x4 __attribute__((ext_vector_type(4)));
typedef unsigned u32x4 __attribute__((ext_vector_type(4)));

__device__ __forceinline__ float b2f(u16 u) { return __uint_as_float(((unsigned)u) << 16); }
__device__ __forceinline__ u16 f2b(float f) {
  unsigned x = __float_as_uint(f);
  unsigned r = x + 0x7fffu + ((x >> 16) & 1u);
  return (u16)(r >> 16);
}
// pack two f32 -> one u32 of 2 bf16 (RNE) in a single HW op
__device__ __forceinline__ unsigned cvtpk(float a, float b) {
  unsigned r;
  asm("v_cvt_pk_bf16_f32 %0, %1, %2" : "=v"(r) : "v"(a), "v"(b));
  return r;
}
union PkH { u32x4 w; s16x8 h; };
union Pk2 { unsigned w[2]; u16x4 h; };

#define SCALE 0.125f
#define DM 512
#define NTOK 32768

typedef __attribute__((address_space(1))) unsigned int as1_u32;
typedef __attribute__((address_space(3))) unsigned int as3_u32;
__device__ __forceinline__ void gl2lds16(const u16* g, u16* s) {
  __builtin_amdgcn_global_load_lds((as1_u32*)g, (as3_u32*)s, 16, 0, 0);
}

// ---------------------------------------------------------------------------
// x fp32 -> bf16 + per-64-token column partial sums (for pooled means)
// ---------------------------------------------------------------------------
__global__ __launch_bounds__(256)
void conv_psum(const float* __restrict__ X, u16* __restrict__ Xb,
               float* __restrict__ Psum)
{
  __shared__ float ps[4][512];
  const int tid = threadIdx.x;
  const int c8 = (tid & 63) * 8;
  const int rg = tid >> 6;
  const size_t tok0 = (size_t)blockIdx.x * 64;
  f32x4 s0 = {0.f, 0.f, 0.f, 0.f}, s1 = {0.f, 0.f, 0.f, 0.f};
  for (int it = 0; it < 16; ++it) {
    const size_t tok = tok0 + it * 4 + rg;
    const float* xp = X + tok * DM + c8;
    f32x4 a = *(const f32x4*)xp;
    f32x4 b = *(const f32x4*)(xp + 4);
    Pk2 p0, p1;
    p0.w[0] = cvtpk(a[0], a[1]); p0.w[1] = cvtpk(a[2], a[3]);
    p1.w[0] = cvtpk(b[0], b[1]); p1.w[1] = cvtpk(b[2], b[3]);
    *(u16x4*)(Xb + tok * DM + c8)     = p0.h;
    *(u16x4*)(Xb + tok * DM + c8 + 4) = p1.h;
    s0 += a; s1 += b;
  }
  *(f32x4*)&ps[rg][c8]     = s0;
  *(f32x4*)&ps[rg][c8 + 4] = s1;
  __syncthreads();
#pragma unroll
  for (int i = 0; i < 2; ++i) {
    const int col = tid + i * 256;
    Psum[(size_t)blockIdx.x * DM + col] =
        ps[0][col] + ps[1][col] + ps[2][col] + ps[3][col];
  }
}

// ---------------------------------------------------------------------------
// transpose-convert 5 weight matrices [512k][512n] fp32 -> Wt [512n][512k] bf16
// ---------------------------------------------------------------------------
__global__ __launch_bounds__(256)
void trans_w(const float* w0, const float* w1, const float* w2,
             const float* w3, const float* w4, u16* __restrict__ WT)
{
  __shared__ float t[32][33];
  const int z = blockIdx.z;
  const float* W = (z == 0) ? w0 : (z == 1) ? w1 : (z == 2) ? w2 : (z == 3) ? w3 : w4;
  u16* D = WT + (size_t)z * DM * DM;
  const int tx = threadIdx.x & 31, ty = threadIdx.x >> 5;
  const int n0 = blockIdx.x * 32, k0 = blockIdx.y * 32;
#pragma unroll
  for (int j = 0; j < 4; ++j)
    t[ty + j * 8][tx] = W[(size_t)(k0 + ty + j * 8) * DM + n0 + tx];
  __syncthreads();
#pragma unroll
  for (int j = 0; j < 4; ++j)
    D[(size_t)(n0 + ty + j * 8) * DM + k0 + tx] = f2b(t[tx][ty + j * 8]);
}

// ---------------------------------------------------------------------------
// MFMA GEMM, 2-phase pipelined (counted vmcnt, never 0 mid-loop):
// 128x128 tile, BK=64, double-buffered linear LDS + global_load_lds.
// EPI 0/1: operand-SWAPPED mfma (lane's 4 regs = 4 consecutive n -> vector
//          row stores). EPI 2: normal order (4 regs = 4 consecutive m) ->
//          u16x4 stores into permuted V^T for the attention PV fragment order.
// EPI 0: Cb[m][n] = bf16((acc+bias[n])*outscale)
// EPI 1: g = sigmoid(acc + GB[brow][n]); Cf = g*A[m][n] + (1-g)*GO[brow][n]
// EPI 2: VT[gh][d][chunk*64 + pos(key)] = bf16(acc + bias[n])
// ---------------------------------------------------------------------------
template<int EPI>
__global__ __launch_bounds__(256)
void gemm_mfma(const u16* __restrict__ A, const u16* __restrict__ Wt,
               const float* __restrict__ bias, u16* __restrict__ Cb,
               float* __restrict__ Cf, float outscale,
               const float* __restrict__ GB, const float* __restrict__ GO)
{
  __shared__ u16 As[2][128 * 64];
  __shared__ u16 Bs[2][128 * 64];
  const int tid = threadIdx.x;
  const int w = tid >> 6, l = tid & 63;
  const int l15 = l & 15, gl = l >> 4;
  const int wm = w >> 1, wn = w & 1;
  const int m0 = blockIdx.y * 128, n0 = blockIdx.x * 128;

  const int srow = l >> 3;
  const int scol = (l & 7) * 8;
  const u16* Ag = A  + (size_t)(m0 + w * 32 + srow) * DM + scol;
  const u16* Bg = Wt + (size_t)(n0 + w * 32 + srow) * DM + scol;

  auto stage = [&](int t, int b) {
    const int k0 = t * 64;
#pragma unroll
    for (int c = 0; c < 4; ++c) {
      gl2lds16(Ag + (size_t)(c * 8) * DM + k0, &As[b][(w * 32 + c * 8) * 64]);
      gl2lds16(Bg + (size_t)(c * 8) * DM + k0, &Bs[b][(w * 32 + c * 8) * 64]);
    }
  };

  f32x4 acc[4][4];
#pragma unroll
  for (int i = 0; i < 4; ++i)
#pragma unroll
    for (int j = 0; j < 4; ++j) acc[i][j] = {0.f, 0.f, 0.f, 0.f};

  stage(0, 0);
#pragma unroll
  for (int t = 0; t < 8; ++t) {
    if (t < 7) {
      stage(t + 1, (t + 1) & 1);
      asm volatile("s_waitcnt vmcnt(8)" ::: "memory");
    } else {
      asm volatile("s_waitcnt vmcnt(0)" ::: "memory");
    }
    __builtin_amdgcn_s_barrier();
    __builtin_amdgcn_sched_barrier(0);
    const int b = t & 1;
#pragma unroll
    for (int kd = 0; kd < 2; ++kd) {
      s16x8 af[4], bfr[4];
#pragma unroll
      for (int f = 0; f < 4; ++f) {
        af[f]  = *(const s16x8*)&As[b][(wm * 64 + f * 16 + l15) * 64 + gl * 8 + kd * 32];
        bfr[f] = *(const s16x8*)&Bs[b][(wn * 64 + f * 16 + l15) * 64 + gl * 8 + kd * 32];
      }
#pragma unroll
      for (int fm = 0; fm < 4; ++fm)
#pragma unroll
        for (int fn = 0; fn < 4; ++fn) {
          if (EPI == 2)
            acc[fm][fn] = __builtin_amdgcn_mfma_f32_16x16x32_bf16(
                af[fm], bfr[fn], acc[fm][fn], 0, 0, 0);
          else
            acc[fm][fn] = __builtin_amdgcn_mfma_f32_16x16x32_bf16(
                bfr[fn], af[fm], acc[fm][fn], 0, 0, 0);
        }
    }
    __builtin_amdgcn_s_barrier();
  }

  if (EPI == 2) {
    // rows = m (4 consecutive tokens per reg), cols = n (d)
#pragma unroll
    for (int fn = 0; fn < 4; ++fn) {
      const int n = n0 + wn * 64 + fn * 16 + l15;
      const float bn = bias[n];
      const int d = n & 63, ghn = n >> 6;
#pragma unroll
      for (int fm = 0; fm < 4; ++fm) {
        const int m = m0 + wm * 64 + fm * 16 + gl * 4;
        const int f = (m & 63) >> 4;
        const int pos = ((f >> 1) << 5) | (gl << 3) | ((f & 1) << 2);
        Pk2 p;
        p.w[0] = cvtpk(acc[fm][fn][0] + bn, acc[fm][fn][1] + bn);
        p.w[1] = cvtpk(acc[fm][fn][2] + bn, acc[fm][fn][3] + bn);
        *(u16x4*)(Cb + ((size_t)(((m >> 9) * 8 + ghn) * 64 + d)) * 512
                     + ((m & 511) >> 6) * 64 + pos) = p.h;
      }
    }
  } else {
    // rows = n (4 consecutive n per reg), cols = m
#pragma unroll
    for (int fm = 0; fm < 4; ++fm) {
      const int m = m0 + wm * 64 + fm * 16 + l15;
      const int brow = m >> 9;
#pragma unroll
      for (int fn = 0; fn < 4; ++fn) {
        const int nb = n0 + wn * 64 + fn * 16 + gl * 4;
        if (EPI == 0) {
          f32x4 b4 = *(const f32x4*)&bias[nb];
          f32x4 v = (acc[fm][fn] + b4) * outscale;
          Pk2 p;
          p.w[0] = cvtpk(v[0], v[1]);
          p.w[1] = cvtpk(v[2], v[3]);
          *(u16x4*)(Cb + (size_t)m * DM + nb) = p.h;
        } else {
          f32x4 z = acc[fm][fn] + *(const f32x4*)&GB[brow * DM + nb];
          u16x4 lo4 = *(const u16x4*)(A + (size_t)m * DM + nb);
          f32x4 go4 = *(const f32x4*)&GO[brow * DM + nb];
          f32x4 res;
#pragma unroll
          for (int r = 0; r < 4; ++r) {
            float g = 1.f / (1.f + __expf(-z[r]));
            res[r] = g * b2f(lo4[r]) + (1.f - g) * go4[r];
          }
          *(f32x4*)(Cf + (size_t)m * DM + nb) = res;
        }
      }
    }
  }
}

// ---------------------------------------------------------------------------
// MFMA flash attention, register-resident P; V^T pre-permuted so PV B-frags
// are single ds_read_b128; next chunk's K/V global loads issued before
// compute (T14). grid (64 g, 8 h, 2 qh), 512 thr = 8 waves, 32 q/wave.
// ---------------------------------------------------------------------------
__global__ __launch_bounds__(512, 4)
void attn_mfma(const u16* __restrict__ Q, const u16* __restrict__ K,
               const u16* __restrict__ VT, u16* __restrict__ CTX)
{
  __shared__ u16 Ks[64][72];      // [key][d]
  __shared__ u16 VsT[64][72];     // [d][permuted key]
  const int tid = threadIdx.x;
  const int w = tid >> 6, l = tid & 63;
  const int l15 = l & 15, gl = l >> 4;
  const int g = blockIdx.x, h = blockIdx.y, qh = blockIdx.z;
  const int t0 = g * 512;
  const int fb = h * 64;
  const int q0 = t0 + qh * 256 + w * 32;
  const u16* VTb = VT + ((size_t)(g * 8 + h) * 64) * 512;

  s16x8 qf[2][2];
#pragma unroll
  for (int fq = 0; fq < 2; ++fq)
#pragma unroll
    for (int kd = 0; kd < 2; ++kd)
      qf[fq][kd] = *(const s16x8*)(Q + (size_t)(q0 + fq * 16 + l15) * DM
                                     + fb + gl * 8 + kd * 32);

  f32x4 o[2][4];
#pragma unroll
  for (int i = 0; i < 2; ++i)
#pragma unroll
    for (int j = 0; j < 4; ++j) o[i][j] = {0.f, 0.f, 0.f, 0.f};
  float m_[2] = {-INFINITY, -INFINITY};
  float l_[2] = {0.f, 0.f};

  const int srow = tid >> 3, sd0 = (tid & 7) * 8;
  const u16* Kg = K + (size_t)(t0 + srow) * DM + fb + sd0;
  const u16* Vg = VTb + (size_t)srow * 512 + sd0;
  s16x8 kreg = *(const s16x8*)Kg;
  s16x8 vreg = *(const s16x8*)Vg;

  for (int kc = 0; kc < 8; ++kc) {
    __syncthreads();
    *(s16x8*)&Ks[srow][sd0]  = kreg;
    *(s16x8*)&VsT[srow][sd0] = vreg;
    __syncthreads();
    if (kc < 7) {   // issue next chunk's loads; they fly during compute
      kreg = *(const s16x8*)(Kg + (size_t)(kc + 1) * 64 * DM);
      vreg = *(const s16x8*)(Vg + (kc + 1) * 64);
    }

    // S^T = K @ Q^T : lane holds P[key=fm*16+gl*4+r][q=fq*16+l15]
    f32x4 s[4][2];
#pragma unroll
    for (int i = 0; i < 4; ++i)
#pragma unroll
      for (int j = 0; j < 2; ++j) s[i][j] = {0.f, 0.f, 0.f, 0.f};
#pragma unroll
    for (int kd = 0; kd < 2; ++kd) {
      s16x8 kf[4];
#pragma unroll
      for (int fm = 0; fm < 4; ++fm)
        kf[fm] = *(const s16x8*)&Ks[fm * 16 + l15][gl * 8 + kd * 32];
#pragma unroll
      for (int fm = 0; fm < 4; ++fm)
#pragma unroll
        for (int fq = 0; fq < 2; ++fq)
          s[fm][fq] = __builtin_amdgcn_mfma_f32_16x16x32_bf16(
              kf[fm], qf[fq][kd], s[fm][fq], 0, 0, 0);
    }

    // online softmax per query column
    float alpha[2];
    PkH pf[2][2];
#pragma unroll
    for (int fq = 0; fq < 2; ++fq) {
      float cm = -INFINITY;
#pragma unroll
      for (int fm = 0; fm < 4; ++fm)
#pragma unroll
        for (int r = 0; r < 4; ++r) cm = fmaxf(cm, s[fm][fq][r]);
      cm = fmaxf(cm, __shfl_xor(cm, 16));
      cm = fmaxf(cm, __shfl_xor(cm, 32));
      const float mnew = fmaxf(m_[fq], cm);
      alpha[fq] = __expf(m_[fq] - mnew);
      m_[fq] = mnew;
      float psum = 0.f;
#pragma unroll
      for (int fm = 0; fm < 4; ++fm)
#pragma unroll
        for (int r = 0; r < 4; ++r) {
          const float p = __expf(s[fm][fq][r] - mnew);
          s[fm][fq][r] = p;
          psum += p;
        }
      psum += __shfl_xor(psum, 16);
      psum += __shfl_xor(psum, 32);
      l_[fq] = l_[fq] * alpha[fq] + psum;
    }
    // pack P -> bf16 A-fragments (keys (2ka+(j>>2))*16+gl*4+(j&3))
#pragma unroll
    for (int ka = 0; ka < 2; ++ka)
#pragma unroll
      for (int fq = 0; fq < 2; ++fq) {
        pf[ka][fq].w[0] = cvtpk(s[2 * ka][fq][0], s[2 * ka][fq][1]);
        pf[ka][fq].w[1] = cvtpk(s[2 * ka][fq][2], s[2 * ka][fq][3]);
        pf[ka][fq].w[2] = cvtpk(s[2 * ka + 1][fq][0], s[2 * ka + 1][fq][1]);
        pf[ka][fq].w[3] = cvtpk(s[2 * ka + 1][fq][2], s[2 * ka + 1][fq][3]);
      }

    // rescale O rows
#pragma unroll
    for (int qm = 0; qm < 2; ++qm) {
      const float a0 = __shfl(alpha[qm], gl * 4 + 0);
      const float a1 = __shfl(alpha[qm], gl * 4 + 1);
      const float a2 = __shfl(alpha[qm], gl * 4 + 2);
      const float a3 = __shfl(alpha[qm], gl * 4 + 3);
#pragma unroll
      for (int fd = 0; fd < 4; ++fd) {
        o[qm][fd][0] *= a0; o[qm][fd][1] *= a1;
        o[qm][fd][2] *= a2; o[qm][fd][3] *= a3;
      }
    }

    // O += P @ V  (V^T pre-permuted: single b128 per fragment)
#pragma unroll
    for (int ka = 0; ka < 2; ++ka)
#pragma unroll
      for (int fd = 0; fd < 4; ++fd) {
        s16x8 vf = *(const s16x8*)&VsT[fd * 16 + l15][ka * 32 + gl * 8];
#pragma unroll
        for (int qm = 0; qm < 2; ++qm)
          o[qm][fd] = __builtin_amdgcn_mfma_f32_16x16x32_bf16(
              pf[ka][qm].h, vf, o[qm][fd], 0, 0, 0);
      }
  }

  // normalize and store
#pragma unroll
  for (int qm = 0; qm < 2; ++qm) {
    const float i0 = 1.f / __shfl(l_[qm], gl * 4 + 0);
    const float i1 = 1.f / __shfl(l_[qm], gl * 4 + 1);
    const float i2 = 1.f / __shfl(l_[qm], gl * 4 + 2);
    const float i3 = 1.f / __shfl(l_[qm], gl * 4 + 3);
#pragma unroll
    for (int fd = 0; fd < 4; ++fd) {
      const size_t base = (size_t)(q0 + qm * 16 + gl * 4) * DM + fb + fd * 16 + l15;
      CTX[base]          = f2b(o[qm][fd][0] * i0);
      CTX[base + DM]     = f2b(o[qm][fd][1] * i1);
      CTX[base + 2 * DM] = f2b(o[qm][fd][2] * i2);
      CTX[base + 3 * DM] = f2b(o[qm][fd][3] * i3);
    }
  }
}

// ---------------------------------------------------------------------------
// pooled means (from Psum) -> Qg/Kg/Vg small GEMMs. grid (64, 3).
// ---------------------------------------------------------------------------
__global__ __launch_bounds__(256)
void small_qkv(const float* __restrict__ Psum,
               const float* __restrict__ Wq, const float* __restrict__ bq,
               const float* __restrict__ Wk, const float* __restrict__ bk,
               const float* __restrict__ Wv, const float* __restrict__ bv,
               float* __restrict__ Qg, float* __restrict__ Kg, float* __restrict__ Vg)
{
  __shared__ float a[512];
  const int g = blockIdx.x, z = blockIdx.y;
  const int tid = threadIdx.x;
  const float* W = (z == 0) ? Wq : (z == 1) ? Wk : Wv;
  const float* b = (z == 0) ? bq : (z == 1) ? bk : bv;
  float* Out     = (z == 0) ? Qg : (z == 1) ? Kg : Vg;
#pragma unroll
  for (int i = 0; i < 2; ++i) {
    const int col = tid + i * 256;
    float v = 0.f;
#pragma unroll
    for (int s = 0; s < 8; ++s) v += Psum[(size_t)(g * 8 + s) * DM + col];
    a[col] = v * (1.f / 512.f);
  }
  __syncthreads();
  float acc0 = 0.f, acc1 = 0.f;
  for (int k = 0; k < DM; ++k) {
    const float av = a[k];
    acc0 = fmaf(av, W[(size_t)k * DM + tid],       acc0);
    acc1 = fmaf(av, W[(size_t)k * DM + tid + 256], acc1);
  }
  Out[(size_t)g * DM + tid]       = acc0 + b[tid];
  Out[(size_t)g * DM + tid + 256] = acc1 + b[tid + 256];
}

// ---------------------------------------------------------------------------
// Global attention over 16 pooled summaries per batch. grid 32: (b, h). fp32.
// ---------------------------------------------------------------------------
__global__ __launch_bounds__(256)
void gattn(const float* __restrict__ Qg, const float* __restrict__ Kg,
           const float* __restrict__ Vg, float* __restrict__ Gl)
{
  __shared__ float q[16][64], k[16][64], v[16][64];
  __shared__ float sc[16][16];
  const int bh = blockIdx.x;
  const int b = bh >> 3, h = bh & 7;
  const int tid = threadIdx.x;
  for (int idx = tid; idx < 1024; idx += 256) {
    const int n = idx >> 6, d = idx & 63;
    const size_t off = (size_t)(b * 16 + n) * DM + h * 64 + d;
    q[n][d] = Qg[off]; k[n][d] = Kg[off]; v[n][d] = Vg[off];
  }
  __syncthreads();
  {
    const int qq = tid >> 4, kk = tid & 15;
    float s = 0.f;
#pragma unroll
    for (int d = 0; d < 64; ++d) s = fmaf(q[qq][d], k[kk][d], s);
    sc[qq][kk] = s * SCALE;
  }
  __syncthreads();
  if (tid < 16) {
    float mx = -INFINITY;
#pragma unroll
    for (int j = 0; j < 16; ++j) mx = fmaxf(mx, sc[tid][j]);
    float e[16]; float sum = 0.f;
#pragma unroll
    for (int j = 0; j < 16; ++j) { e[j] = __expf(sc[tid][j] - mx); sum += e[j]; }
    const float inv = 1.f / sum;
#pragma unroll
    for (int j = 0; j < 16; ++j) sc[tid][j] = e[j] * inv;
  }
  __syncthreads();
  for (int idx = tid; idx < 1024; idx += 256) {
    const int qq = idx >> 6, d = idx & 63;
    float o = 0.f;
#pragma unroll
    for (int j = 0; j < 16; ++j) o = fmaf(sc[qq][j], v[j][d], o);
    Gl[(size_t)(b * 16 + qq) * DM + h * 64 + d] = o;
  }
}

// ---------------------------------------------------------------------------
// GOUT[r] = Gl[r] @ go_w + go_b ; GATEBLK[r] = GOUT[r] @ gate_w2 + gate_b
// ---------------------------------------------------------------------------
__global__ __launch_bounds__(256)
void go_gate(const float* __restrict__ Gl,
             const float* __restrict__ go_w, const float* __restrict__ go_b,
             const float* __restrict__ gw2, const float* __restrict__ gate_b,
             float* __restrict__ GOUT, float* __restrict__ GATEBLK)
{
  __shared__ float a[512];
  const int r = blockIdx.x, tid = threadIdx.x;
  a[tid]       = Gl[(size_t)r * DM + tid];
  a[tid + 256] = Gl[(size_t)r * DM + tid + 256];
  __syncthreads();
  float acc0 = 0.f, acc1 = 0.f;
  for (int k = 0; k < DM; ++k) {
    const float av = a[k];
    acc0 = fmaf(av, go_w[(size_t)k * DM + tid],       acc0);
    acc1 = fmaf(av, go_w[(size_t)k * DM + tid + 256], acc1);
  }
  acc0 += go_b[tid]; acc1 += go_b[tid + 256];
  GOUT[(size_t)r * DM + tid]       = acc0;
  GOUT[(size_t)r * DM + tid + 256] = acc1;
  __syncthreads();
  a[tid] = acc0; a[tid + 256] = acc1;
  __syncthreads();
  float g0 = 0.f, g1 = 0.f;
  for (int k = 0; k < DM; ++k) {
    const float av = a[k];
    g0 = fmaf(av, gw2[(size_t)k * DM + tid],       g0);
    g1 = fmaf(av, gw2[(size_t)k * DM + tid + 256], g1);
  }
  GATEBLK[(size_t)r * DM + tid]       = g0 + gate_b[tid];
  GATEBLK[(size_t)r * DM + tid + 256] = g1 + gate_b[tid + 256];
}

// ---------------------------------------------------------------------------
extern "C" void kernel_launch(void* const* d_in, const int* in_sizes, int n_in,
                              void* d_out, int out_size, void* d_ws, size_t ws_size,
                              hipStream_t stream)
{
  const float* x      = (const float*)d_in[0];
  const float* lq_w   = (const float*)d_in[1];
  const float* lq_b   = (const float*)d_in[2];
  const float* lk_w   = (const float*)d_in[3];
  const float* lk_b   = (const float*)d_in[4];
  const float* lv_w   = (const float*)d_in[5];
  const float* lv_b   = (const float*)d_in[6];
  const float* lo_w   = (const float*)d_in[7];
  const float* lo_b   = (const float*)d_in[8];
  const float* gq_w   = (const float*)d_in[9];
  const float* gq_b   = (const float*)d_in[10];
  const float* gk_w   = (const float*)d_in[11];
  const float* gk_b   = (const float*)d_in[12];
  const float* gv_w   = (const float*)d_in[13];
  const float* gv_b   = (const float*)d_in[14];
  const float* go_w   = (const float*)d_in[15];
  const float* go_b   = (const float*)d_in[16];
  const float* gate_w = (const float*)d_in[17];
  const float* gate_b = (const float*)d_in[18];
  float* out = (float*)d_out;

  const size_t NE = (size_t)NTOK * DM;
  char* ws = (char*)d_ws;
  u16* Qb = (u16*)ws;                    // 32 MiB; CTX aliases
  u16* Kb = Qb + NE;                     // 32 MiB
  u16* VT = Kb + NE;                     // 32 MiB, V^T permuted per (g,h)
  u16* WT = VT + NE;                     // 5 x 512x512 bf16
  float* scr     = (float*)(WT + (size_t)5 * DM * DM);
  float* Psum    = scr;                  // 512 x 512 f32
  float* Qg      = Psum + 512 * DM;
  float* Kg      = Qg + 64 * DM;
  float* Vg      = Kg + 64 * DM;
  float* Gl      = Vg + 64 * DM;
  float* GOUT    = Gl + 64 * DM;
  float* GATEBLK = GOUT + 64 * DM;
  u16* xb = (u16*)d_out;                 // bf16 x lives in d_out until final GEMM
  u16* LOCAL = Kb;                       // Kb dead after attention

  u16* WTq = WT;
  u16* WTk = WT + (size_t)1 * DM * DM;
  u16* WTv = WT + (size_t)2 * DM * DM;
  u16* WTo = WT + (size_t)3 * DM * DM;
  u16* WTg = WT + (size_t)4 * DM * DM;

  conv_psum<<<512, 256, 0, stream>>>(x, xb, Psum);
  trans_w<<<dim3(16, 16, 5), 256, 0, stream>>>(lq_w, lk_w, lv_w, lo_w, gate_w, WT);

  const dim3 gg(4, 256), bb(256);
  gemm_mfma<0><<<gg, bb, 0, stream>>>(xb, WTq, lq_b, Qb, nullptr, SCALE, nullptr, nullptr);
  gemm_mfma<0><<<gg, bb, 0, stream>>>(xb, WTk, lk_b, Kb, nullptr, 1.0f, nullptr, nullptr);
  gemm_mfma<2><<<gg, bb, 0, stream>>>(xb, WTv, lv_b, VT, nullptr, 1.0f, nullptr, nullptr);
  attn_mfma<<<dim3(64, 8, 2), 512, 0, stream>>>(Qb, Kb, VT, Qb /*CTX*/);
  gemm_mfma<0><<<gg, bb, 0, stream>>>(Qb /*CTX*/, WTo, lo_b, LOCAL, nullptr, 1.0f, nullptr, nullptr);

  small_qkv<<<dim3(64, 3), 256, 0, stream>>>(Psum, gq_w, gq_b, gk_w, gk_b, gv_w, gv_b, Qg, Kg, Vg);
  gattn<<<32, 256, 0, stream>>>(Qg, Kg, Vg, Gl);
  go_gate<<<64, 256, 0, stream>>>(Gl, go_w, go_b, gate_w + (size_t)DM * DM, gate_b, GOUT, GATEBLK);

  gemm_mfma<1><<<gg, bb, 0, stream>>>(LOCAL, WTg, nullptr, nullptr, out, 1.0f, GATEBLK, GOUT);
}

// Round 6
// 278.498 us; speedup vs baseline: 7.9817x; 1.1973x over previous
//
#include <hip/hip_runtime.h>
#include <math.h>

typedef unsigned short u16;
typedef short s16;
typedef u16 u16x8 __attribute__((ext_vector_type(8)));
typedef u16 u16x4 __attribute__((ext_vector_type(4)));
typedef s16 s16x8 __attribute__((ext_vector_type(8)));
typedef float f32x4 __attribute__((ext_vector_type(4)));
typedef unsigned u32x4 __attribute__((ext_vector_type(4)));

__device__ __forceinline__ float b2f(u16 u) { return __uint_as_float(((unsigned)u) << 16); }
__device__ __forceinline__ u16 f2b(float f) {
  unsigned x = __float_as_uint(f);
  unsigned r = x + 0x7fffu + ((x >> 16) & 1u);
  return (u16)(r >> 16);
}
__device__ __forceinline__ unsigned cvtpk(float a, float b) {
  unsigned r;
  asm("v_cvt_pk_bf16_f32 %0, %1, %2" : "=v"(r) : "v"(a), "v"(b));
  return r;
}
union PkH { u32x4 w; s16x8 h; };
union Pk2 { unsigned w[2]; u16x4 h; };

#define SCALE 0.125f
#define DM 512
#define NTOK 32768

typedef __attribute__((address_space(1))) unsigned int as1_u32;
typedef __attribute__((address_space(3))) unsigned int as3_u32;
__device__ __forceinline__ void gl2lds16(const u16* g, u16* s) {
  __builtin_amdgcn_global_load_lds((as1_u32*)g, (as3_u32*)s, 16, 0, 0);
}

// ---------------------------------------------------------------------------
// x fp32 -> bf16 + per-64-token column partial sums (for pooled means)
// ---------------------------------------------------------------------------
__global__ __launch_bounds__(256)
void conv_psum(const float* __restrict__ X, u16* __restrict__ Xb,
               float* __restrict__ Psum)
{
  __shared__ float ps[4][512];
  const int tid = threadIdx.x;
  const int c8 = (tid & 63) * 8;
  const int rg = tid >> 6;
  const size_t tok0 = (size_t)blockIdx.x * 64;
  f32x4 s0 = {0.f, 0.f, 0.f, 0.f}, s1 = {0.f, 0.f, 0.f, 0.f};
  for (int it = 0; it < 16; ++it) {
    const size_t tok = tok0 + it * 4 + rg;
    const float* xp = X + tok * DM + c8;
    f32x4 a = *(const f32x4*)xp;
    f32x4 b = *(const f32x4*)(xp + 4);
    Pk2 p0, p1;
    p0.w[0] = cvtpk(a[0], a[1]); p0.w[1] = cvtpk(a[2], a[3]);
    p1.w[0] = cvtpk(b[0], b[1]); p1.w[1] = cvtpk(b[2], b[3]);
    *(u16x4*)(Xb + tok * DM + c8)     = p0.h;
    *(u16x4*)(Xb + tok * DM + c8 + 4) = p1.h;
    s0 += a; s1 += b;
  }
  *(f32x4*)&ps[rg][c8]     = s0;
  *(f32x4*)&ps[rg][c8 + 4] = s1;
  __syncthreads();
#pragma unroll
  for (int i = 0; i < 2; ++i) {
    const int col = tid + i * 256;
    Psum[(size_t)blockIdx.x * DM + col] =
        ps[0][col] + ps[1][col] + ps[2][col] + ps[3][col];
  }
}

// ---------------------------------------------------------------------------
// pooled block means -> bf16: pooledB[g][c] = (sum of 8 Psum rows)/512
// ---------------------------------------------------------------------------
__global__ __launch_bounds__(256)
void pool_prep(const float* __restrict__ Psum, u16* __restrict__ PB)
{
  const int g = blockIdx.x, tid = threadIdx.x;
#pragma unroll
  for (int i = 0; i < 2; ++i) {
    const int col = tid + i * 256;
    float v = 0.f;
#pragma unroll
    for (int s = 0; s < 8; ++s) v += Psum[(size_t)(g * 8 + s) * DM + col];
    PB[(size_t)g * DM + col] = f2b(v * (1.f / 512.f));
  }
}

// ---------------------------------------------------------------------------
// transpose-convert 10 weight matrices [512k][512n] fp32 -> Wt [512n][512k] bf16
// ---------------------------------------------------------------------------
__global__ __launch_bounds__(256)
void trans_w(const float* w0, const float* w1, const float* w2, const float* w3,
             const float* w4, const float* w5, const float* w6, const float* w7,
             const float* w8, const float* w9, u16* __restrict__ WT)
{
  __shared__ float t[32][33];
  const int z = blockIdx.z;
  const float* W = (z == 0) ? w0 : (z == 1) ? w1 : (z == 2) ? w2 : (z == 3) ? w3 :
                   (z == 4) ? w4 : (z == 5) ? w5 : (z == 6) ? w6 : (z == 7) ? w7 :
                   (z == 8) ? w8 : w9;
  u16* D = WT + (size_t)z * DM * DM;
  const int tx = threadIdx.x & 31, ty = threadIdx.x >> 5;
  const int n0 = blockIdx.x * 32, k0 = blockIdx.y * 32;
#pragma unroll
  for (int j = 0; j < 4; ++j)
    t[ty + j * 8][tx] = W[(size_t)(k0 + ty + j * 8) * DM + n0 + tx];
  __syncthreads();
#pragma unroll
  for (int j = 0; j < 4; ++j)
    D[(size_t)(n0 + ty + j * 8) * DM + k0 + tx] = f2b(t[tx][ty + j * 8]);
}

// ---------------------------------------------------------------------------
// direct fp32 -> bf16 convert of one 512x512 weight (go_w, A of combine GEMM)
// ---------------------------------------------------------------------------
__global__ __launch_bounds__(256)
void conv_w(const float* __restrict__ W, u16* __restrict__ D)
{
  const size_t i = ((size_t)blockIdx.x * 256 + threadIdx.x) * 8;
  f32x4 a = *(const f32x4*)(W + i);
  f32x4 b = *(const f32x4*)(W + i + 4);
  Pk2 p0, p1;
  p0.w[0] = cvtpk(a[0], a[1]); p0.w[1] = cvtpk(a[2], a[3]);
  p1.w[0] = cvtpk(b[0], b[1]); p1.w[1] = cvtpk(b[2], b[3]);
  *(u16x4*)(D + i)     = p0.h;
  *(u16x4*)(D + i + 4) = p1.h;
}

// ---------------------------------------------------------------------------
// bc[j] = sum_k go_b[k] * gw2[k][j] + gate_b[j]   (gw2 = gate_w rows 512..1023)
// grid 16, block 256: block covers 32 j; 8 k-parts of 64, LDS reduce.
// ---------------------------------------------------------------------------
__global__ __launch_bounds__(256)
void bc_kernel(const float* __restrict__ go_b, const float* __restrict__ gate_w,
               const float* __restrict__ gate_b, float* __restrict__ bc)
{
  __shared__ float red[8][32];
  const int tid = threadIdx.x;
  const int jj = tid & 31, part = tid >> 5;
  const int j = blockIdx.x * 32 + jj;
  float p = 0.f;
#pragma unroll
  for (int i = 0; i < 64; ++i) {
    const int k = part * 64 + i;
    p = fmaf(go_b[k], gate_w[(size_t)(512 + k) * DM + j], p);
  }
  red[part][jj] = p;
  __syncthreads();
  if (tid < 32) {
    float v = gate_b[blockIdx.x * 32 + tid];
#pragma unroll
    for (int s = 0; s < 8; ++s) v += red[s][tid];
    bc[blockIdx.x * 32 + tid] = v;
  }
}

// ---------------------------------------------------------------------------
// MFMA GEMM, 2-phase pipelined, bank-conflict-free LDS (source-pre-swizzled
// granules, XOR'd reads). 128x128 tile, BK=64.
// EPI 0: Cb[m][n] = bf16((acc+bias[n])*outscale)
// EPI 1: g = sigmoid(acc + GG[brow][512+n]); Cf = g*A[m][n] + (1-g)*GG[brow][n]
// EPI 2: permuted V^T store for attention PV fragment order
// EPI 3: Cb[m][n] = bf16(acc)   (no bias; weight-combine output)
// ---------------------------------------------------------------------------
template<int EPI>
__global__ __launch_bounds__(256)
void gemm_mfma(const u16* __restrict__ A, const u16* __restrict__ Wt,
               const float* __restrict__ bias, u16* __restrict__ Cb,
               float* __restrict__ Cf, float outscale,
               const float* __restrict__ GG)
{
  __shared__ u16 As[2][128 * 64];
  __shared__ u16 Bs[2][128 * 64];
  const int tid = threadIdx.x;
  const int w = tid >> 6, l = tid & 63;
  const int l15 = l & 15, gl = l >> 4;
  const int wm = w >> 1, wn = w & 1;
  const int m0 = blockIdx.y * 128, n0 = blockIdx.x * 128;

  const int srow = l >> 3;
  const int scol = ((l & 7) ^ (srow & 7)) * 8;     // pre-swizzled source granule
  const u16* Ag = A  + (size_t)(m0 + w * 32 + srow) * DM + scol;
  const u16* Bg = Wt + (size_t)(n0 + w * 32 + srow) * DM + scol;

  auto stage = [&](int t, int b) {
    const int k0 = t * 64;
#pragma unroll
    for (int c = 0; c < 4; ++c) {
      gl2lds16(Ag + (size_t)(c * 8) * DM + k0, &As[b][(w * 32 + c * 8) * 64]);
      gl2lds16(Bg + (size_t)(c * 8) * DM + k0, &Bs[b][(w * 32 + c * 8) * 64]);
    }
  };

  f32x4 acc[4][4];
#pragma unroll
  for (int i = 0; i < 4; ++i)
#pragma unroll
    for (int j = 0; j < 4; ++j) acc[i][j] = {0.f, 0.f, 0.f, 0.f};

  const int xorv = l15 & 7;
  stage(0, 0);
#pragma unroll
  for (int t = 0; t < 8; ++t) {
    if (t < 7) {
      stage(t + 1, (t + 1) & 1);
      asm volatile("s_waitcnt vmcnt(8)" ::: "memory");
    } else {
      asm volatile("s_waitcnt vmcnt(0)" ::: "memory");
    }
    __builtin_amdgcn_s_barrier();
    __builtin_amdgcn_sched_barrier(0);
    const int b = t & 1;
#pragma unroll
    for (int kd = 0; kd < 2; ++kd) {
      const int go = ((gl + 4 * kd) ^ xorv) * 8;
      s16x8 af[4], bfr[4];
#pragma unroll
      for (int f = 0; f < 4; ++f) {
        af[f]  = *(const s16x8*)&As[b][(wm * 64 + f * 16 + l15) * 64 + go];
        bfr[f] = *(const s16x8*)&Bs[b][(wn * 64 + f * 16 + l15) * 64 + go];
      }
#pragma unroll
      for (int fm = 0; fm < 4; ++fm)
#pragma unroll
        for (int fn = 0; fn < 4; ++fn) {
          if (EPI == 2)
            acc[fm][fn] = __builtin_amdgcn_mfma_f32_16x16x32_bf16(
                af[fm], bfr[fn], acc[fm][fn], 0, 0, 0);
          else
            acc[fm][fn] = __builtin_amdgcn_mfma_f32_16x16x32_bf16(
                bfr[fn], af[fm], acc[fm][fn], 0, 0, 0);
        }
    }
    __builtin_amdgcn_s_barrier();
  }

  if (EPI == 2) {
#pragma unroll
    for (int fn = 0; fn < 4; ++fn) {
      const int n = n0 + wn * 64 + fn * 16 + l15;
      const float bn = bias[n];
      const int d = n & 63, ghn = n >> 6;
#pragma unroll
      for (int fm = 0; fm < 4; ++fm) {
        const int m = m0 + wm * 64 + fm * 16 + gl * 4;
        const int f = (m & 63) >> 4;
        const int pos = ((f >> 1) << 5) | (gl << 3) | ((f & 1) << 2);
        Pk2 p;
        p.w[0] = cvtpk(acc[fm][fn][0] + bn, acc[fm][fn][1] + bn);
        p.w[1] = cvtpk(acc[fm][fn][2] + bn, acc[fm][fn][3] + bn);
        *(u16x4*)(Cb + ((size_t)(((m >> 9) * 8 + ghn) * 64 + d)) * 512
                     + ((m & 511) >> 6) * 64 + pos) = p.h;
      }
    }
  } else {
#pragma unroll
    for (int fm = 0; fm < 4; ++fm) {
      const int m = m0 + wm * 64 + fm * 16 + l15;
      const int brow = m >> 9;
#pragma unroll
      for (int fn = 0; fn < 4; ++fn) {
        const int nb = n0 + wn * 64 + fn * 16 + gl * 4;
        if (EPI == 0) {
          f32x4 b4 = *(const f32x4*)&bias[nb];
          f32x4 v = (acc[fm][fn] + b4) * outscale;
          Pk2 p;
          p.w[0] = cvtpk(v[0], v[1]);
          p.w[1] = cvtpk(v[2], v[3]);
          *(u16x4*)(Cb + (size_t)m * DM + nb) = p.h;
        } else if (EPI == 3) {
          Pk2 p;
          p.w[0] = cvtpk(acc[fm][fn][0], acc[fm][fn][1]);
          p.w[1] = cvtpk(acc[fm][fn][2], acc[fm][fn][3]);
          *(u16x4*)(Cb + (size_t)m * DM + nb) = p.h;
        } else {
          f32x4 z = acc[fm][fn] + *(const f32x4*)&GG[(size_t)brow * 1024 + 512 + nb];
          u16x4 lo4 = *(const u16x4*)(A + (size_t)m * DM + nb);
          f32x4 go4 = *(const f32x4*)&GG[(size_t)brow * 1024 + nb];
          f32x4 res;
#pragma unroll
          for (int r = 0; r < 4; ++r) {
            float g = 1.f / (1.f + __expf(-z[r]));
            res[r] = g * b2f(lo4[r]) + (1.f - g) * go4[r];
          }
          *(f32x4*)(Cf + (size_t)m * DM + nb) = res;
        }
      }
    }
  }
}

// ---------------------------------------------------------------------------
// Small MFMA GEMM: Out[64 x (grid*128)] fp32 = A[64x512](bf16) @ Bsel^T + bias
// BM=64, BN=128/block, BK=64, 2-phase counted-vmcnt pipeline, swizzled LDS.
// Block bx uses B/bias pair (bx>>2) with column offset (bx&3)*128.
// ---------------------------------------------------------------------------
__global__ __launch_bounds__(256)
void gemm64(const u16* __restrict__ A,
            const u16* B0, const u16* B1, const u16* B2,
            const float* b0, const float* b1, const float* b2,
            float* __restrict__ Out, int ldo)
{
  __shared__ u16 As[2][64 * 64];
  __shared__ u16 Bs[2][128 * 64];
  const int tid = threadIdx.x;
  const int w = tid >> 6, l = tid & 63;
  const int l15 = l & 15, gl = l >> 4;
  const int bx = blockIdx.x;
  const int grp = bx >> 2;
  const u16* Bt = ((grp == 0) ? B0 : (grp == 1) ? B1 : B2)
                  + (size_t)(bx & 3) * 128 * DM;
  const float* bias = (grp == 0) ? b0 : (grp == 1) ? b1 : b2;

  const int srow = l >> 3;
  const int scol = ((l & 7) ^ (srow & 7)) * 8;
  const u16* Ag = A  + (size_t)(w * 16 + srow) * DM + scol;
  const u16* Bg = Bt + (size_t)(w * 32 + srow) * DM + scol;

  auto stage = [&](int t, int b) {
    const int k0 = t * 64;
#pragma unroll
    for (int c = 0; c < 2; ++c)
      gl2lds16(Ag + (size_t)(c * 8) * DM + k0, &As[b][(w * 16 + c * 8) * 64]);
#pragma unroll
    for (int c = 0; c < 4; ++c)
      gl2lds16(Bg + (size_t)(c * 8) * DM + k0, &Bs[b][(w * 32 + c * 8) * 64]);
  };

  f32x4 acc[4][2];
#pragma unroll
  for (int i = 0; i < 4; ++i)
#pragma unroll
    for (int j = 0; j < 2; ++j) acc[i][j] = {0.f, 0.f, 0.f, 0.f};

  const int xorv = l15 & 7;
  stage(0, 0);
#pragma unroll
  for (int t = 0; t < 8; ++t) {
    if (t < 7) {
      stage(t + 1, (t + 1) & 1);
      asm volatile("s_waitcnt vmcnt(6)" ::: "memory");
    } else {
      asm volatile("s_waitcnt vmcnt(0)" ::: "memory");
    }
    __builtin_amdgcn_s_barrier();
    __builtin_amdgcn_sched_barrier(0);
    const int b = t & 1;
#pragma unroll
    for (int kd = 0; kd < 2; ++kd) {
      const int go = ((gl + 4 * kd) ^ xorv) * 8;
      s16x8 af[4], bfr[2];
#pragma unroll
      for (int f = 0; f < 4; ++f)
        af[f] = *(const s16x8*)&As[b][(f * 16 + l15) * 64 + go];
#pragma unroll
      for (int f = 0; f < 2; ++f)
        bfr[f] = *(const s16x8*)&Bs[b][(w * 32 + f * 16 + l15) * 64 + go];
#pragma unroll
      for (int fm = 0; fm < 4; ++fm)
#pragma unroll
        for (int fn = 0; fn < 2; ++fn)
          acc[fm][fn] = __builtin_amdgcn_mfma_f32_16x16x32_bf16(
              bfr[fn], af[fm], acc[fm][fn], 0, 0, 0);
    }
    __builtin_amdgcn_s_barrier();
  }

#pragma unroll
  for (int fm = 0; fm < 4; ++fm) {
    const int m = fm * 16 + l15;
#pragma unroll
    for (int fn = 0; fn < 2; ++fn) {
      const int nloc = w * 32 + fn * 16 + gl * 4;
      f32x4 b4 = *(const f32x4*)&bias[(bx & 3) * 128 + nloc];
      *(f32x4*)&Out[(size_t)m * ldo + bx * 128 + nloc] = acc[fm][fn] + b4;
    }
  }
}

// ---------------------------------------------------------------------------
// MFMA flash attention (unchanged from round 5, validated)
// ---------------------------------------------------------------------------
__global__ __launch_bounds__(512, 4)
void attn_mfma(const u16* __restrict__ Q, const u16* __restrict__ K,
               const u16* __restrict__ VT, u16* __restrict__ CTX)
{
  __shared__ u16 Ks[64][72];
  __shared__ u16 VsT[64][72];
  const int tid = threadIdx.x;
  const int w = tid >> 6, l = tid & 63;
  const int l15 = l & 15, gl = l >> 4;
  const int g = blockIdx.x, h = blockIdx.y, qh = blockIdx.z;
  const int t0 = g * 512;
  const int fb = h * 64;
  const int q0 = t0 + qh * 256 + w * 32;
  const u16* VTb = VT + ((size_t)(g * 8 + h) * 64) * 512;

  s16x8 qf[2][2];
#pragma unroll
  for (int fq = 0; fq < 2; ++fq)
#pragma unroll
    for (int kd = 0; kd < 2; ++kd)
      qf[fq][kd] = *(const s16x8*)(Q + (size_t)(q0 + fq * 16 + l15) * DM
                                     + fb + gl * 8 + kd * 32);

  f32x4 o[2][4];
#pragma unroll
  for (int i = 0; i < 2; ++i)
#pragma unroll
    for (int j = 0; j < 4; ++j) o[i][j] = {0.f, 0.f, 0.f, 0.f};
  float m_[2] = {-INFINITY, -INFINITY};
  float l_[2] = {0.f, 0.f};

  const int srow = tid >> 3, sd0 = (tid & 7) * 8;
  const u16* Kg = K + (size_t)(t0 + srow) * DM + fb + sd0;
  const u16* Vg = VTb + (size_t)srow * 512 + sd0;
  s16x8 kreg = *(const s16x8*)Kg;
  s16x8 vreg = *(const s16x8*)Vg;

  for (int kc = 0; kc < 8; ++kc) {
    __syncthreads();
    *(s16x8*)&Ks[srow][sd0]  = kreg;
    *(s16x8*)&VsT[srow][sd0] = vreg;
    __syncthreads();
    if (kc < 7) {
      kreg = *(const s16x8*)(Kg + (size_t)(kc + 1) * 64 * DM);
      vreg = *(const s16x8*)(Vg + (kc + 1) * 64);
    }

    f32x4 s[4][2];
#pragma unroll
    for (int i = 0; i < 4; ++i)
#pragma unroll
      for (int j = 0; j < 2; ++j) s[i][j] = {0.f, 0.f, 0.f, 0.f};
#pragma unroll
    for (int kd = 0; kd < 2; ++kd) {
      s16x8 kf[4];
#pragma unroll
      for (int fm = 0; fm < 4; ++fm)
        kf[fm] = *(const s16x8*)&Ks[fm * 16 + l15][gl * 8 + kd * 32];
#pragma unroll
      for (int fm = 0; fm < 4; ++fm)
#pragma unroll
        for (int fq = 0; fq < 2; ++fq)
          s[fm][fq] = __builtin_amdgcn_mfma_f32_16x16x32_bf16(
              kf[fm], qf[fq][kd], s[fm][fq], 0, 0, 0);
    }

    float alpha[2];
    PkH pf[2][2];
#pragma unroll
    for (int fq = 0; fq < 2; ++fq) {
      float cm = -INFINITY;
#pragma unroll
      for (int fm = 0; fm < 4; ++fm)
#pragma unroll
        for (int r = 0; r < 4; ++r) cm = fmaxf(cm, s[fm][fq][r]);
      cm = fmaxf(cm, __shfl_xor(cm, 16));
      cm = fmaxf(cm, __shfl_xor(cm, 32));
      const float mnew = fmaxf(m_[fq], cm);
      alpha[fq] = __expf(m_[fq] - mnew);
      m_[fq] = mnew;
      float psum = 0.f;
#pragma unroll
      for (int fm = 0; fm < 4; ++fm)
#pragma unroll
        for (int r = 0; r < 4; ++r) {
          const float p = __expf(s[fm][fq][r] - mnew);
          s[fm][fq][r] = p;
          psum += p;
        }
      psum += __shfl_xor(psum, 16);
      psum += __shfl_xor(psum, 32);
      l_[fq] = l_[fq] * alpha[fq] + psum;
    }
#pragma unroll
    for (int ka = 0; ka < 2; ++ka)
#pragma unroll
      for (int fq = 0; fq < 2; ++fq) {
        pf[ka][fq].w[0] = cvtpk(s[2 * ka][fq][0], s[2 * ka][fq][1]);
        pf[ka][fq].w[1] = cvtpk(s[2 * ka][fq][2], s[2 * ka][fq][3]);
        pf[ka][fq].w[2] = cvtpk(s[2 * ka + 1][fq][0], s[2 * ka + 1][fq][1]);
        pf[ka][fq].w[3] = cvtpk(s[2 * ka + 1][fq][2], s[2 * ka + 1][fq][3]);
      }

#pragma unroll
    for (int qm = 0; qm < 2; ++qm) {
      const float a0 = __shfl(alpha[qm], gl * 4 + 0);
      const float a1 = __shfl(alpha[qm], gl * 4 + 1);
      const float a2 = __shfl(alpha[qm], gl * 4 + 2);
      const float a3 = __shfl(alpha[qm], gl * 4 + 3);
#pragma unroll
      for (int fd = 0; fd < 4; ++fd) {
        o[qm][fd][0] *= a0; o[qm][fd][1] *= a1;
        o[qm][fd][2] *= a2; o[qm][fd][3] *= a3;
      }
    }

#pragma unroll
    for (int ka = 0; ka < 2; ++ka)
#pragma unroll
      for (int fd = 0; fd < 4; ++fd) {
        s16x8 vf = *(const s16x8*)&VsT[fd * 16 + l15][ka * 32 + gl * 8];
#pragma unroll
        for (int qm = 0; qm < 2; ++qm)
          o[qm][fd] = __builtin_amdgcn_mfma_f32_16x16x32_bf16(
              pf[ka][qm].h, vf, o[qm][fd], 0, 0, 0);
      }
  }

#pragma unroll
  for (int qm = 0; qm < 2; ++qm) {
    const float i0 = 1.f / __shfl(l_[qm], gl * 4 + 0);
    const float i1 = 1.f / __shfl(l_[qm], gl * 4 + 1);
    const float i2 = 1.f / __shfl(l_[qm], gl * 4 + 2);
    const float i3 = 1.f / __shfl(l_[qm], gl * 4 + 3);
#pragma unroll
    for (int fd = 0; fd < 4; ++fd) {
      const size_t base = (size_t)(q0 + qm * 16 + gl * 4) * DM + fb + fd * 16 + l15;
      CTX[base]          = f2b(o[qm][fd][0] * i0);
      CTX[base + DM]     = f2b(o[qm][fd][1] * i1);
      CTX[base + 2 * DM] = f2b(o[qm][fd][2] * i2);
      CTX[base + 3 * DM] = f2b(o[qm][fd][3] * i3);
    }
  }
}

// ---------------------------------------------------------------------------
// Global attention over 16 pooled summaries per batch. grid 32: (b, h).
// Reads QKVg fp32 [64][1536]; writes Gl bf16 [64][512].
// ---------------------------------------------------------------------------
__global__ __launch_bounds__(256)
void gattn(const float* __restrict__ QKVg, u16* __restrict__ GlB)
{
  __shared__ float q[16][64], k[16][64], v[16][64];
  __shared__ float sc[16][16];
  const int bh = blockIdx.x;
  const int b = bh >> 3, h = bh & 7;
  const int tid = threadIdx.x;
  for (int idx = tid; idx < 1024; idx += 256) {
    const int n = idx >> 6, d = idx & 63;
    const size_t off = (size_t)(b * 16 + n) * 1536 + h * 64 + d;
    q[n][d] = QKVg[off]; k[n][d] = QKVg[off + 512]; v[n][d] = QKVg[off + 1024];
  }
  __syncthreads();
  {
    const int qq = tid >> 4, kk = tid & 15;
    float s = 0.f;
#pragma unroll
    for (int d = 0; d < 64; ++d) s = fmaf(q[qq][d], k[kk][d], s);
    sc[qq][kk] = s * SCALE;
  }
  __syncthreads();
  if (tid < 16) {
    float mx = -INFINITY;
#pragma unroll
    for (int j = 0; j < 16; ++j) mx = fmaxf(mx, sc[tid][j]);
    float e[16]; float sum = 0.f;
#pragma unroll
    for (int j = 0; j < 16; ++j) { e[j] = __expf(sc[tid][j] - mx); sum += e[j]; }
    const float inv = 1.f / sum;
#pragma unroll
    for (int j = 0; j < 16; ++j) sc[tid][j] = e[j] * inv;
  }
  __syncthreads();
  for (int idx = tid; idx < 1024; idx += 256) {
    const int qq = idx >> 6, d = idx & 63;
    float o = 0.f;
#pragma unroll
    for (int j = 0; j < 16; ++j) o = fmaf(sc[qq][j], v[j][d], o);
    GlB[(size_t)(b * 16 + qq) * DM + h * 64 + d] = f2b(o);
  }
}

// ---------------------------------------------------------------------------
extern "C" void kernel_launch(void* const* d_in, const int* in_sizes, int n_in,
                              void* d_out, int out_size, void* d_ws, size_t ws_size,
                              hipStream_t stream)
{
  const float* x      = (const float*)d_in[0];
  const float* lq_w   = (const float*)d_in[1];
  const float* lq_b   = (const float*)d_in[2];
  const float* lk_w   = (const float*)d_in[3];
  const float* lk_b   = (const float*)d_in[4];
  const float* lv_w   = (const float*)d_in[5];
  const float* lv_b   = (const float*)d_in[6];
  const float* lo_w   = (const float*)d_in[7];
  const float* lo_b   = (const float*)d_in[8];
  const float* gq_w   = (const float*)d_in[9];
  const float* gq_b   = (const float*)d_in[10];
  const float* gk_w   = (const float*)d_in[11];
  const float* gk_b   = (const float*)d_in[12];
  const float* gv_w   = (const float*)d_in[13];
  const float* gv_b   = (const float*)d_in[14];
  const float* go_w   = (const float*)d_in[15];
  const float* go_b   = (const float*)d_in[16];
  const float* gate_w = (const float*)d_in[17];
  const float* gate_b = (const float*)d_in[18];
  float* out = (float*)d_out;

  const size_t NE = (size_t)NTOK * DM;
  const size_t DD = (size_t)DM * DM;
  char* ws = (char*)d_ws;
  u16* Qb  = (u16*)ws;                   // 32 MiB; CTX aliases
  u16* Kb  = Qb + NE;                    // 32 MiB; LOCAL aliases after attn
  u16* VT  = Kb + NE;                    // 32 MiB
  u16* WT  = VT + NE;                    // 10 x 512x512 bf16 = 5 MiB
  u16* goD = WT + 10 * DD;               // 0.5 MiB (go_w direct bf16)
  u16* WcT = goD + DD;                   // 0.5 MiB (combined gate weight ^T)
  u16* PB  = WcT + DD;                   // pooled bf16 [64][512]
  u16* GlB = PB + 64 * DM;               // global-attn out bf16 [64][512]
  float* scr  = (float*)(GlB + 64 * DM);
  float* Psum = scr;                     // 512x512 fp32
  float* QKVg = Psum + 512 * DM;         // [64][1536] fp32
  float* GG   = QKVg + (size_t)64 * 1536;// [64][1024] fp32 (GOUT | GATEBLK)
  float* bc   = GG + (size_t)64 * 1024;  // [512] fp32
  u16* xb = (u16*)d_out;                 // bf16 x in d_out until final GEMM
  u16* LOCAL = Kb;

  u16* WTq  = WT;
  u16* WTk  = WT + 1 * DD;
  u16* WTv  = WT + 2 * DD;
  u16* WTo  = WT + 3 * DD;
  u16* WTg  = WT + 4 * DD;
  u16* WTgq = WT + 5 * DD;
  u16* WTgk = WT + 6 * DD;
  u16* WTgv = WT + 7 * DD;
  u16* WTgo = WT + 8 * DD;
  u16* WTg2 = WT + 9 * DD;               // gw2^T (A of combine)

  conv_psum<<<512, 256, 0, stream>>>(x, xb, Psum);
  trans_w<<<dim3(16, 16, 10), 256, 0, stream>>>(
      lq_w, lk_w, lv_w, lo_w, gate_w, gq_w, gk_w, gv_w, go_w,
      gate_w + DD, WT);
  conv_w<<<128, 256, 0, stream>>>(go_w, goD);
  bc_kernel<<<16, 256, 0, stream>>>(go_b, gate_w, gate_b, bc);
  pool_prep<<<64, 256, 0, stream>>>(Psum, PB);

  const dim3 gg(4, 256), bb(256);
  gemm_mfma<0><<<gg, bb, 0, stream>>>(xb, WTq, lq_b, Qb, nullptr, SCALE, nullptr);
  gemm_mfma<0><<<gg, bb, 0, stream>>>(xb, WTk, lk_b, Kb, nullptr, 1.0f, nullptr);
  gemm_mfma<2><<<gg, bb, 0, stream>>>(xb, WTv, lv_b, VT, nullptr, 1.0f, nullptr);
  // WcT[j][i] = sum_k gw2[k][j] * go_w[i][k]  (combined gate weight, bf16)
  gemm_mfma<3><<<dim3(4, 4), bb, 0, stream>>>(WTg2, goD, nullptr, WcT, nullptr, 1.0f, nullptr);

  attn_mfma<<<dim3(64, 8, 2), 512, 0, stream>>>(Qb, Kb, VT, Qb /*CTX*/);
  gemm_mfma<0><<<gg, bb, 0, stream>>>(Qb /*CTX*/, WTo, lo_b, LOCAL, nullptr, 1.0f, nullptr);

  // small path: QKVg = pooled @ [gq|gk|gv] + biases ; gattn ; GG = Gl @ [go|Wc]
  gemm64<<<12, 256, 0, stream>>>(PB, WTgq, WTgk, WTgv, gq_b, gk_b, gv_b, QKVg, 1536);
  gattn<<<32, 256, 0, stream>>>(QKVg, GlB);
  gemm64<<<8, 256, 0, stream>>>(GlB, WTgo, WcT, WcT, go_b, bc, bc, GG, 1024);

  gemm_mfma<1><<<gg, bb, 0, stream>>>(LOCAL, WTg, nullptr, nullptr, out, 1.0f, GG);
}